// Round 2
// baseline (417.688 us; speedup 1.0000x reference)
//
#include <hip/hip_runtime.h>
#include <math.h>

#define DI __device__ __forceinline__

namespace {

constexpr int B_ = 16;
constexpr int N_ = 1025;
constexpr int C_ = 384;
constexpr int H_ = 6;
constexpr int HD_ = 64;
constexpr int HID_ = 1536;
constexpr int P_ = 1024;          // spatial tokens (32x32)
constexpr int MTOK = B_ * P_;     // 16384
constexpr int MALL = B_ * N_;     // 16400
constexpr int NPAD = 1088;        // padded key stride for V^T (16B-aligned rows)
constexpr long long AF = (long long)MALL * C_;  // 6297600 elems

// weight-conversion segment bounds (contiguous bf16 dst)
constexpr int NQKV = 3 * C_ * C_;     // 442368
constexpr int NPROJ = C_ * C_;        // 147456
constexpr int NC1 = HID_ * C_;        // 589824
constexpr int NC3 = C_ * HID_;        // 589824
constexpr int NW2 = HID_ * 9;         // 13824
constexpr int T1 = NQKV, T2 = T1 + NPROJ, T3 = T2 + NC1, T4 = T3 + NC3;
constexpr int T5 = T4 + NW2, T6 = T5 + HID_;

typedef __attribute__((ext_vector_type(4))) float f32x4;
typedef __attribute__((ext_vector_type(16))) float f32x16;
typedef __attribute__((ext_vector_type(8))) short bf16x8;

DI float gelu_f(float x) { return 0.5f * x * (1.0f + erff(x * 0.7071067811865475f)); }

DI float us2f(unsigned short u) {
  union { unsigned int i; float f; } c; c.i = ((unsigned)u) << 16; return c.f;
}
DI unsigned short f2us(float f) {
  union { float f; unsigned int i; } c; c.f = f;
  unsigned int r = c.i + 0x7FFF + ((c.i >> 16) & 1);
  return (unsigned short)(r >> 16);
}
DI unsigned short f2us_trunc(float f) {   // truncation: 1 shift, no round
  union { float f; unsigned int i; } c; c.f = f;
  return (unsigned short)(c.i >> 16);
}
DI void bf8_to_f(const uint4 v, float* f) {
  const unsigned int u[4] = {v.x, v.y, v.z, v.w};
#pragma unroll
  for (int t = 0; t < 4; t++) {
    union { unsigned int i; float fl; } lo, hi;
    lo.i = (u[t] & 0xffffu) << 16;
    hi.i = u[t] & 0xffff0000u;
    f[2 * t] = lo.fl; f[2 * t + 1] = hi.fl;
  }
}
DI uint4 f_to_bf8(const float* f) {
  unsigned int w[4];
#pragma unroll
  for (int t = 0; t < 4; t++)
    w[t] = (unsigned)f2us(f[2 * t]) | ((unsigned)f2us(f[2 * t + 1]) << 16);
  return make_uint4(w[0], w[1], w[2], w[3]);
}

// pack two f32 -> one dword of two bf16 (RNE), the T12 primitive
DI unsigned cvt_pk_bf16(float lo, float hi) {
  unsigned d;
  asm("v_cvt_pk_bf16_f32 %0, %1, %2" : "=v"(d) : "v"(lo), "v"(hi));
  return d;
}
// exchange a.hi32lanes <-> b.lo32lanes: after call, a = lo-half values in both
// halves' roles per T12 word-assembly; see fattn comments.
DI void permswap(unsigned &a, unsigned &b) {
  asm("v_permlane32_swap_b32 %0, %1" : "+v"(a), "+v"(b));
}

// async global -> LDS, 16 B per lane (lane i lands at ldsbase + i*16)
DI void gl2lds16(const unsigned short* g, unsigned short* l) {
  __builtin_amdgcn_global_load_lds(
      (const __attribute__((address_space(1))) void*)g,
      (__attribute__((address_space(3))) void*)l, 16, 0, 0);
}

// ---------------- fused weight conversion / prep (one launch) ----------------
// dst16 layout (contiguous): [qkv | proj | conv1 | conv3 | w2s(tap-major, BN folded)]
__global__ __launch_bounds__(256) void cvtall_kernel(
    const float* __restrict__ qkv_w, const float* __restrict__ proj_w,
    const float* __restrict__ conv1_w, const float* __restrict__ conv3_w,
    const float* __restrict__ conv2_w, const float* __restrict__ c2b,
    const float* __restrict__ s2, const float* __restrict__ b2,
    unsigned short* __restrict__ dst16, float* __restrict__ Bc)
{
  const int idx = blockIdx.x * 256 + threadIdx.x;
  if (idx < T1)      dst16[idx] = f2us(qkv_w[idx]);
  else if (idx < T2) dst16[idx] = f2us(proj_w[idx - T1]);
  else if (idx < T3) dst16[idx] = f2us(conv1_w[idx - T2]);
  else if (idx < T4) dst16[idx] = f2us(conv3_w[idx - T3]);
  else if (idx < T5) {
    const int r = idx - T4, tap = r / HID_, c = r % HID_;
    dst16[idx] = f2us(conv2_w[c * 9 + tap] * s2[c]);
  } else if (idx < T6) {
    const int c = idx - T5;
    Bc[c] = c2b[c] * s2[c] + b2[c];
  }
}

// ---------------- LayerNorm, wave-per-row (no LDS, shfl reduce), bf16 out ----------------
__global__ __launch_bounds__(256) void lnw_kernel(
    const float* __restrict__ x, const float* __restrict__ g,
    const float* __restrict__ b, unsigned short* __restrict__ out,
    float* __restrict__ cls_out, int nrows)
{
  const int row = blockIdx.x * 4 + (threadIdx.x >> 6);   // wave-uniform
  if (row >= nrows) return;
  const int lane = threadIdx.x & 63;
  const float* xr = x + (long long)row * C_;
  float v[6];
#pragma unroll
  for (int i = 0; i < 6; i++) v[i] = xr[lane + 64 * i];
  float s = 0.f, q = 0.f;
#pragma unroll
  for (int i = 0; i < 6; i++) { s += v[i]; q += v[i] * v[i]; }
#pragma unroll
  for (int m = 1; m < 64; m <<= 1) {
    s += __shfl_xor(s, m, 64);
    q += __shfl_xor(q, m, 64);
  }
  const float mean = s * (1.0f / C_);
  const float var  = q * (1.0f / C_) - mean * mean;
  const float rstd = rsqrtf(var + 1e-5f);
  unsigned short* orow = out + (long long)row * C_;
  const bool iscls = (cls_out != nullptr) && (row % N_) == 0;
  float* cr = iscls ? cls_out + (long long)(row / N_) * C_ : nullptr;
#pragma unroll
  for (int i = 0; i < 6; i++) {
    const int c = lane + 64 * i;
    const float r = (v[i] - mean) * rstd * g[c] + b[c];
    orow[c] = f2us(r);
    if (iscls) cr[c] = r;
  }
}

// ---------------- V transpose: (bh,n,d) -> (bh,d,n) padded, zero-filled tail ----------------
__global__ __launch_bounds__(256) void vtrans_kernel(
    const unsigned short* __restrict__ v, unsigned short* __restrict__ vt)
{
  __shared__ unsigned short t[64][72];
  const int bh = blockIdx.x, nt = blockIdx.y;
  const int n0 = nt * 64;
  const int tid = threadIdx.x;
  {
    const int nl = tid >> 2;            // 0..63
    const int dc = (tid & 3) * 16;      // 0,16,32,48
    const int gn = n0 + nl;
    uint4 a = make_uint4(0u,0u,0u,0u), b = make_uint4(0u,0u,0u,0u);
    if (gn < N_) {
      const unsigned short* p = v + ((long long)bh * N_ + gn) * HD_ + dc;
      a = *(const uint4*)p; b = *(const uint4*)(p + 8);
    }
    *(uint4*)&t[nl][dc] = a;
    *(uint4*)&t[nl][dc + 8] = b;
  }
  __syncthreads();
  {
    const int dl = tid >> 2;            // 0..63
    const int nc = (tid & 3) * 16;
    unsigned short tmp[16];
#pragma unroll
    for (int i = 0; i < 16; i++) tmp[i] = t[nc + i][dl];
    unsigned short* p = vt + ((long long)bh * HD_ + dl) * NPAD + n0 + nc;
    *(uint4*)p = *(uint4*)&tmp[0];
    *(uint4*)(p + 8) = *(uint4*)&tmp[8];
  }
}

// ---------------- bf16 MFMA GEMM with global_load_lds staging ----------------
// CONV3 epilogue also writes out = x2 + y3 directly to d_out token rows
// (o1 = d_out, o2 = x2); y3 raw kept for the pool.
enum { GM_QKV = 0, GM_PROJ = 1, GM_CONV1 = 2, GM_CONV3 = 3 };

template <int MODE, int K>
__global__ __launch_bounds__(256) void mgemm_kernel(
    const unsigned short* __restrict__ A, const unsigned short* __restrict__ W,
    void* __restrict__ o0, void* __restrict__ o1, void* __restrict__ o2,
    const float* __restrict__ e0, const float* __restrict__ e1,
    const float* __restrict__ e2, int M)
{
  __shared__ unsigned short As[128][64];
  __shared__ unsigned short Bs[128][64];
  const int m0 = blockIdx.x * 128, n0 = blockIdx.y * 128;
  if (m0 >= M) return;   // grid padded to multiple-of-8 m-tiles
  const int tid = threadIdx.x;
  const int lane = tid & 63, wv = tid >> 6;
  const int lane15 = lane & 15, quad = lane >> 4;
  const int wm = (wv >> 1) * 64, wn = (wv & 1) * 64;

  const unsigned short* agp[4];
  const unsigned short* bgp[4];
#pragma unroll
  for (int t = 0; t < 4; t++) {
    const int lr = wv * 32 + t * 8 + (lane >> 3);
    const int chunk = (lane & 7) ^ (lr & 7);
    int gm = m0 + lr;
    if (gm > M - 1) gm = M - 1;                  // clamp; epilogue masks m>=M
    long long arow = gm;
    if constexpr (MODE == GM_CONV1) arow = (long long)(gm >> 10) * N_ + 1 + (gm & 1023);
    agp[t] = A + arow * K + chunk * 8;
    bgp[t] = W + (long long)(n0 + lr) * K + chunk * 8;
  }

  f32x4 acc[4][4];
#pragma unroll
  for (int i = 0; i < 4; i++)
#pragma unroll
    for (int j = 0; j < 4; j++) acc[i][j] = (f32x4)0.f;

  const int xsel = lane15 & 7;
  for (int k0 = 0; k0 < K; k0 += 64) {
    __syncthreads();
#pragma unroll
    for (int t = 0; t < 4; t++) {
      gl2lds16(agp[t] + k0, &As[wv * 32 + t * 8][0]);
      gl2lds16(bgp[t] + k0, &Bs[wv * 32 + t * 8][0]);
    }
    __syncthreads();
#pragma unroll
    for (int kh = 0; kh < 2; kh++) {
      bf16x8 af[4], bfr[4];
#pragma unroll
      for (int i = 0; i < 4; i++)
        af[i] = *(const bf16x8*)&As[wm + i * 16 + lane15][((kh * 4 + quad) ^ xsel) * 8];
#pragma unroll
      for (int j = 0; j < 4; j++)
        bfr[j] = *(const bf16x8*)&Bs[wn + j * 16 + lane15][((kh * 4 + quad) ^ xsel) * 8];
#pragma unroll
      for (int i = 0; i < 4; i++)
#pragma unroll
        for (int j = 0; j < 4; j++)
          acc[i][j] = __builtin_amdgcn_mfma_f32_16x16x32_bf16(af[i], bfr[j], acc[i][j], 0, 0, 0);
    }
  }
  // epilogue: C/D layout col=lane&15, row=quad*4+r
#pragma unroll
  for (int i = 0; i < 4; i++) {
#pragma unroll
    for (int r = 0; r < 4; r++) {
      const int m = m0 + wm + i * 16 + quad * 4 + r;
      if (m >= M) continue;
#pragma unroll
      for (int j = 0; j < 4; j++) {
        const int n = n0 + wn + j * 16 + lane15;
        const float val = acc[i][j][r];
        if constexpr (MODE == GM_QKV) {
          const int which = n / C_, rr = n % C_, hh = rr >> 6, e = rr & 63;
          const int b = m / N_, nn = m % N_;
          unsigned short* dst = (unsigned short*)((which == 0) ? o0 : ((which == 1) ? o1 : o2));
          // fold softmax scale AND log2(e) into Q (softmax uses exp2)
          const float sval = (which == 0) ? val * 0.18033688f : val;
          dst[(((long long)b * H_ + hh) * N_ + nn) * HD_ + e] = f2us(sval);
        } else if constexpr (MODE == GM_PROJ) {
          ((float*)o0)[(long long)m * C_ + n] = val + e0[(long long)m * C_ + n] + e1[n];
        } else if constexpr (MODE == GM_CONV1) {
          ((unsigned short*)o0)[(long long)m * HID_ + n] =
              f2us(gelu_f((val + e0[n]) * e1[n] + e2[n]));
        } else {  // GM_CONV3: y3 raw + fused residual out
          const float val2 = (val + e0[n]) * e1[n] + e2[n];
          ((float*)o0)[(long long)m * C_ + n] = val2;
          const int bb = m >> 10, pp = m & 1023;
          // x2 and out are both (b, 1+p, c) rows over N_=1025 — SAME index
          const long long orow = ((long long)bb * N_ + 1 + pp) * C_ + n;
          ((float*)o1)[orow] = ((const float*)o2)[orow] + val2;
        }
      }
    }
  }
}

// ---------------- Flash attention: 32x32x16 MFMA, swapped QK^T, in-register
// softmax (T12: cvt_pk_bf16 + permlane32_swap), no P LDS round-trip.
// 4 waves x 32 q-rows = 128 q-tile; dbuf K/V staging, 1 barrier/tile.
// S^T = mfma(A=K, B=Q^T): lane holds P[q=lane&31][k=(r&3)+8*(r>>2)+4*half+32*b].
// PV A-frag(kc): word t: t<2 -> lo.pk[4*kc+2*half+t], t>=2 -> hi.pk[4*kc+2*half+t-2];
// one permlane32_swap(pk[s], pk[s+2]) yields (w0,w2) [resp (w1,w3)] for all lanes.
__global__ __launch_bounds__(256) void fattn_kernel(
    const unsigned short* __restrict__ q, const unsigned short* __restrict__ k,
    const unsigned short* __restrict__ vt, unsigned short* __restrict__ o)
{
  __shared__ unsigned short Ks[2][64][64];   // [buf][key][d]   8-chunk XOR swizzle
  __shared__ unsigned short Vt[2][64][64];   // [buf][d][key]   8-chunk XOR swizzle
  const int tid = threadIdx.x;
  const int lane = tid & 63, wv = tid >> 6;          // wv 0..3
  const int lane31 = lane & 31, half = lane >> 5;
  const int x7 = lane & 7;
  const int bh = blockIdx.x, qt = blockIdx.y;
  const long long headoff = (long long)bh * N_;
  const int q0w = qt * 128 + wv * 32;
  const bool active = q0w < N_;            // wave-uniform; OOB waves only stage

  // Q fragments: lane holds Q[q=lane31][d = m*16 + half*8 + j]
  int gq = q0w + lane31; if (gq > N_ - 1) gq = N_ - 1;
  const unsigned short* qp = q + (headoff + gq) * HD_ + half * 8;
  bf16x8 qf[4];
#pragma unroll
  for (int m = 0; m < 4; m++) qf[m] = *(const bf16x8*)(qp + m * 16);

  // staging: 2 issues/array/tile; issue t covers rows t*32 + wv*8 + (lane>>3)
  const unsigned short* kgp[2];
  const unsigned short* vgp[2];
#pragma unroll
  for (int t = 0; t < 2; t++) {
    const int r = t * 32 + wv * 8 + (lane >> 3);
    const int ch = (lane & 7) ^ (r & 7);
    kgp[t] = k + (headoff + r) * HD_ + ch * 8;
    vgp[t] = vt + ((long long)bh * HD_ + r) * NPAD + ch * 8;
  }

  f32x16 O0 = (f32x16)0.f, O1 = (f32x16)0.f;   // O[q=crow(r,half)][d=lane31+db*32]
  float l = 0.f;

  // prologue: stage tile 0 into buffer 0
#pragma unroll
  for (int t = 0; t < 2; t++) {
    gl2lds16(kgp[t], &Ks[0][t * 32 + wv * 8][0]);
    gl2lds16(vgp[t], &Vt[0][t * 32 + wv * 8][0]);
  }
  __syncthreads();

  for (int kt = 0; kt < 17; kt++) {
    const int cur = kt & 1;
    if (kt < 16) {
      const long long koff = (long long)(kt + 1) * 64;
#pragma unroll
      for (int t = 0; t < 2; t++) {
        gl2lds16(kgp[t] + koff * HD_, &Ks[cur ^ 1][t * 32 + wv * 8][0]);
        gl2lds16(vgp[t] + koff, &Vt[cur ^ 1][t * 32 + wv * 8][0]);
      }
    }
    if (active) {
      // S^T = K Q^T  (log2e and 1/8 scale pre-folded into Q)
      f32x16 S0 = (f32x16)0.f, S1 = (f32x16)0.f;
      __builtin_amdgcn_s_setprio(1);
#pragma unroll
      for (int m = 0; m < 4; m++) {
        const int chs = ((m * 2 + half) ^ x7) * 8;
        const bf16x8 k0 = *(const bf16x8*)&Ks[cur][lane31][chs];
        const bf16x8 k1 = *(const bf16x8*)&Ks[cur][32 + lane31][chs];
        S0 = __builtin_amdgcn_mfma_f32_32x32x16_bf16(k0, qf[m], S0, 0, 0, 0);
        S1 = __builtin_amdgcn_mfma_f32_32x32x16_bf16(k1, qf[m], S1, 0, 0, 0);
      }
      __builtin_amdgcn_s_setprio(0);
      if (kt == 16) {                    // mask OOB keys (only k_glob=1024 valid)
#pragma unroll
        for (int r = 0; r < 16; r++) {
          const int kl = (r & 3) + 8 * (r >> 2) + 4 * half;
          if (1024 + kl >= N_) S0[r] = -1e30f;
          S1[r] = -1e30f;
        }
      }
      // P = 2^S in-register; pack pairs (k even,k odd) -> bf16 dwords
      unsigned pk0[8], pk1[8];
#pragma unroll
      for (int s = 0; s < 8; s++) {
        const float a0 = exp2f(S0[2 * s]), a1 = exp2f(S0[2 * s + 1]);
        const float b0 = exp2f(S1[2 * s]), b1 = exp2f(S1[2 * s + 1]);
        l += (a0 + a1) + (b0 + b1);
        pk0[s] = cvt_pk_bf16(a0, a1);
        pk1[s] = cvt_pk_bf16(b0, b1);
      }
      // assemble PV A-fragments via permlane32_swap (4 swaps per 32k-block)
      unsigned wkc[4][4];
#pragma unroll
      for (int bb = 0; bb < 2; bb++) {
#pragma unroll
        for (int kc2 = 0; kc2 < 2; kc2++) {
          unsigned a0 = bb ? pk1[kc2 * 4 + 0] : pk0[kc2 * 4 + 0];
          unsigned a2 = bb ? pk1[kc2 * 4 + 2] : pk0[kc2 * 4 + 2];
          permswap(a0, a2);
          unsigned a1 = bb ? pk1[kc2 * 4 + 1] : pk0[kc2 * 4 + 1];
          unsigned a3 = bb ? pk1[kc2 * 4 + 3] : pk0[kc2 * 4 + 3];
          permswap(a1, a3);
          const int kc = bb * 2 + kc2;
          wkc[kc][0] = a0; wkc[kc][1] = a1; wkc[kc][2] = a2; wkc[kc][3] = a3;
        }
      }
      // O += P V  (B-frag from Vt: V[k][d] = Vt[d][k], d=lane31+db*32)
      __builtin_amdgcn_s_setprio(1);
#pragma unroll
      for (int kc = 0; kc < 4; kc++) {
        union { unsigned u[4]; bf16x8 v; } pa;
        pa.u[0] = wkc[kc][0]; pa.u[1] = wkc[kc][1];
        pa.u[2] = wkc[kc][2]; pa.u[3] = wkc[kc][3];
        const int chv = ((kc * 2 + half) ^ x7) * 8;
        const bf16x8 v0 = *(const bf16x8*)&Vt[cur][lane31][chv];
        const bf16x8 v1 = *(const bf16x8*)&Vt[cur][32 + lane31][chv];
        O0 = __builtin_amdgcn_mfma_f32_32x32x16_bf16(pa.v, v0, O0, 0, 0, 0);
        O1 = __builtin_amdgcn_mfma_f32_32x32x16_bf16(pa.v, v1, O1, 0, 0, 0);
      }
      __builtin_amdgcn_s_setprio(0);
    }
    // one barrier per tile: drains own async loads AND guards buffer reuse
    __syncthreads();
  }

  // l: lane holds partial for q=lane31 over its half's k-classes; merge halves
  l += __shfl_xor(l, 32, 64);
  const float rinv = 1.0f / l;
  // redistribute 1/l to output rows: O row q = (r&3)+8*(r>>2)+4*half
  float li[16];
#pragma unroll
  for (int r = 0; r < 16; r++) {
    const int qloc = (r & 3) + 8 * (r >> 2) + 4 * half;
    li[r] = __int_as_float(
        __builtin_amdgcn_ds_bpermute(qloc * 4, __float_as_int(rinv)));
  }
  const int b = bh / H_, hh = bh % H_;
#pragma unroll
  for (int r = 0; r < 16; r++) {
    const int qloc = (r & 3) + 8 * (r >> 2) + 4 * half;
    const int gqr = q0w + qloc;
    if (gqr < N_) {
      const long long orow = ((long long)b * N_ + gqr) * C_ + hh * HD_;
      o[orow + lane31] = f2us(O0[r] * li[r]);
      o[orow + 32 + lane31] = f2us(O1[r] * li[r]);
    }
  }
}

// ---------------- Depthwise 3x3, 2 tokens/thread sliding window ----------------
// block = (b, i, j-pair); 192 threads each own 8 channels for both j0=2jp, j1=2jp+1.
// 12 uint4 data loads cover both outputs; weights unpacked once; shortcut = center taps.
__global__ __launch_bounds__(192) void dwconv_kernel(
    const unsigned short* __restrict__ y1, const unsigned short* __restrict__ w2s,
    const float* __restrict__ Bc, unsigned short* __restrict__ y2)
{
  const int jp = blockIdx.x & 15;
  const int i  = (blockIdx.x >> 4) & 31;
  const int b  = blockIdx.x >> 9;
  const int j0 = jp * 2;
  const int cb = threadIdx.x << 3;

  float wf[9][8];
#pragma unroll
  for (int tap = 0; tap < 9; tap++) {
    const uint4 wv = *(const uint4*)(w2s + tap * HID_ + cb);
    bf8_to_f(wv, wf[tap]);
  }
  float acc0[8] = {}, acc1[8] = {};
  float sh0[8], sh1[8];
#pragma unroll
  for (int di = -1; di <= 1; di++) {
    const int ii = i + di;
    if (ii < 0 || ii > 31) continue;
    const long long rowbase = ((long long)b * P_ + ii * 32) * HID_ + cb;
#pragma unroll
    for (int dj = -1; dj <= 2; dj++) {
      const int jj = j0 + dj;
      if (jj < 0 || jj > 31) continue;
      const uint4 dv = *(const uint4*)(y1 + rowbase + (long long)jj * HID_);
      float df[8]; bf8_to_f(dv, df);
      if (dj <= 1) {
        const int tap = (di + 1) * 3 + (dj + 1);
#pragma unroll
        for (int t = 0; t < 8; t++) acc0[t] += df[t] * wf[tap][t];
      }
      if (dj >= 0) {
        const int tap = (di + 1) * 3 + dj;
#pragma unroll
        for (int t = 0; t < 8; t++) acc1[t] += df[t] * wf[tap][t];
      }
      if (di == 0 && dj == 0) {
#pragma unroll
        for (int t = 0; t < 8; t++) sh0[t] = df[t];
      }
      if (di == 0 && dj == 1) {
#pragma unroll
        for (int t = 0; t < 8; t++) sh1[t] = df[t];
      }
    }
  }
  const float4 bc0 = *(const float4*)(Bc + cb);
  const float4 bc1 = *(const float4*)(Bc + cb + 4);
  const float bcv[8] = {bc0.x, bc0.y, bc0.z, bc0.w, bc1.x, bc1.y, bc1.z, bc1.w};
  float of0[8], of1[8];
#pragma unroll
  for (int t = 0; t < 8; t++) {
    of0[t] = sh0[t] + gelu_f(acc0[t] + bcv[t]);
    of1[t] = sh1[t] + gelu_f(acc1[t] + bcv[t]);
  }
  const long long tok0 = ((long long)b * P_ + i * 32 + j0) * HID_ + cb;
  *(uint4*)(y2 + tok0) = f_to_bf8(of0);
  *(uint4*)(y2 + tok0 + HID_) = f_to_bf8(of1);
}

// ---------------- Spatial pooling (two-stage, no atomics) ----------------
__global__ __launch_bounds__(384) void pool_kernel(const float* __restrict__ y3,
                                                   float* __restrict__ w0p)
{
  const int b = blockIdx.x, chunk = blockIdx.y;
  const int c = threadIdx.x;
  float s = 0.f;
  for (int p = chunk * 64; p < chunk * 64 + 64; p++)
    s += y3[((long long)b * P_ + p) * C_ + c];
  w0p[((long long)b * 16 + chunk) * C_ + c] = s;
}

// ---------------- Squeeze-excite MLP ----------------
__global__ __launch_bounds__(128) void se_kernel(
    const float* __restrict__ w0p, const float* __restrict__ cw,
    const float* __restrict__ cb, const float* __restrict__ ew,
    const float* __restrict__ eb, float* __restrict__ wfin)
{
  __shared__ float wm[384];
  __shared__ float t1[96];
  const int b = blockIdx.x, t = threadIdx.x;
  for (int c = t; c < 384; c += 128) {
    float s = 0.f;
    for (int ch = 0; ch < 16; ch++) s += w0p[((long long)b * 16 + ch) * C_ + c];
    wm[c] = s * (1.0f / 1024.0f);
  }
  __syncthreads();
  if (t < 96) {
    float s = cb[t];
    for (int c = 0; c < 384; c++) s += wm[c] * cw[t * 384 + c];
    t1[t] = gelu_f(s);
  }
  __syncthreads();
  for (int c = t; c < 384; c += 128) {
    float s = eb[c];
    for (int j = 0; j < 96; j++) s += t1[j] * ew[c * 96 + j];
    wfin[(long long)b * C_ + c] = s;
  }
}

// ---------------- cls rows: out[b,0,:] = x2[b,0,:] + cls*wfin ----------------
__global__ __launch_bounds__(256) void clsfix_kernel(
    const float* __restrict__ x2, const float* __restrict__ cls,
    const float* __restrict__ wfin, float* __restrict__ out)
{
  const int idx = blockIdx.x * 256 + threadIdx.x;
  if (idx >= B_ * C_) return;
  const int b = idx / C_, c = idx % C_;
  const long long row = (long long)b * N_ * C_ + c;
  out[row] = x2[row] + cls[idx] * wfin[idx];
}

}  // namespace

// Workspace layout (bytes), total ~130 MiB:
//   RegionA [0, 50331648):            q,k,v bf16 -> h2 bf16 -> y2 bf16
//   RegionB [50331648, 100663296):    h bf16 -> o_mat bf16 -> y1 bf16 -> y3 fp32
//   RegionC [100663296, 125853696):   vT bf16 (during attention) -> x2 fp32
//   tail:                             bf16 weights(contig)+w2s, Bc, cls, w0p, wfin
extern "C" void kernel_launch(void* const* d_in, const int* in_sizes, int n_in,
                              void* d_out, int out_size, void* d_ws, size_t ws_size,
                              hipStream_t stream)
{
  const float* x       = (const float*)d_in[0];
  const float* ln1_g   = (const float*)d_in[1];
  const float* ln1_b   = (const float*)d_in[2];
  const float* qkv_w   = (const float*)d_in[3];
  const float* proj_w  = (const float*)d_in[4];
  const float* proj_b  = (const float*)d_in[5];
  const float* ln2_g   = (const float*)d_in[6];
  const float* ln2_b   = (const float*)d_in[7];
  const float* conv1_w = (const float*)d_in[8];
  const float* conv1_b = (const float*)d_in[9];
  const float* conv2_w = (const float*)d_in[10];
  const float* conv2_b = (const float*)d_in[11];
  const float* conv3_w = (const float*)d_in[12];
  const float* conv3_b = (const float*)d_in[13];
  const float* bn1_s   = (const float*)d_in[14];
  const float* bn1_b   = (const float*)d_in[15];
  const float* bn2_s   = (const float*)d_in[16];
  const float* bn2_b   = (const float*)d_in[17];
  const float* bn3_s   = (const float*)d_in[18];
  const float* bn3_b   = (const float*)d_in[19];
  const float* comp_w  = (const float*)d_in[20];
  const float* comp_b  = (const float*)d_in[21];
  const float* exc_w   = (const float*)d_in[22];
  const float* exc_b   = (const float*)d_in[23];

  char* wsb = (char*)d_ws;
  const size_t RA = 50331648, RB = 50331648, RC = 25190400;
  const size_t tailbytes = (size_t)T5 * 2 +
                           (size_t)(HID_ + B_ * C_ + B_ * 16 * C_ + B_ * C_) * 4;
  const size_t needed = RA + RB + RC + tailbytes;
  if (ws_size < needed) return;

  unsigned short* qb  = (unsigned short*)wsb;
  unsigned short* kb  = qb + AF;
  unsigned short* vb  = kb + AF;
  unsigned short* h2b = (unsigned short*)wsb;          // overlay RA
  unsigned short* y2  = (unsigned short*)wsb;          // overlay RA
  char* rb = wsb + RA;
  unsigned short* hb  = (unsigned short*)rb;           // LN1 out
  unsigned short* o16 = (unsigned short*)rb;           // attn out (overlay)
  unsigned short* y1  = (unsigned short*)rb;           // conv1 out (overlay)
  float* y3           = (float*)rb;                    // conv3 out (overlay)
  unsigned short* vtb = (unsigned short*)(wsb + RA + RB);  // V^T (overlay RC)
  float* x2 = (float*)(wsb + RA + RB);                     // x2 after attention
  unsigned short* w16 = (unsigned short*)(wsb + RA + RB + RC);  // contiguous weights
  unsigned short* wqkv16  = w16;
  unsigned short* wproj16 = w16 + T1;
  unsigned short* wc116   = w16 + T2;
  unsigned short* wc316   = w16 + T3;
  unsigned short* w2s     = w16 + T4;
  float* Bc   = (float*)(w16 + T5);
  float* cls  = Bc + HID_;
  float* w0p  = cls + B_ * C_;
  float* wfin = w0p + B_ * 16 * C_;

  // 0. fused weight conversion / prep (1 launch)
  cvtall_kernel<<<(T6 + 255) / 256, 256, 0, stream>>>(
      qkv_w, proj_w, conv1_w, conv3_w, conv2_w, conv2_b, bn2_s, bn2_b, w16, Bc);
  // 1. LN1 -> bf16 (wave-per-row)
  lnw_kernel<<<(MALL + 3) / 4, 256, 0, stream>>>(x, ln1_g, ln1_b, hb, nullptr, MALL);
  // 2. QKV MFMA GEMM (Q pre-scaled by 0.125*log2e)
  mgemm_kernel<GM_QKV, 384><<<dim3(136, 9), 256, 0, stream>>>(
      hb, wqkv16, qb, kb, vb, nullptr, nullptr, nullptr, MALL);
  // 2b. V transpose -> vT (bh, d, n) padded
  vtrans_kernel<<<dim3(B_ * H_, 17), 256, 0, stream>>>(vb, vtb);
  // 3. Flash attention (32x32 swapped-QK^T, in-register softmax)
  fattn_kernel<<<dim3(B_ * H_, 9), 256, 0, stream>>>(qb, kb, vtb, o16);
  // 4. proj MFMA GEMM + residual -> x2 fp32 (overwrites vT region)
  mgemm_kernel<GM_PROJ, 384><<<dim3(136, 3), 256, 0, stream>>>(
      o16, wproj16, x2, nullptr, nullptr, x, proj_b, nullptr, MALL);
  // 5. LN2 -> bf16 h2 (+ fp32 cls rows)
  lnw_kernel<<<(MALL + 3) / 4, 256, 0, stream>>>(x2, ln2_g, ln2_b, h2b, cls, MALL);
  // 6. conv1 MFMA GEMM + bias/BN/GELU -> y1 bf16
  mgemm_kernel<GM_CONV1, 384><<<dim3(128, 12), 256, 0, stream>>>(
      h2b, wc116, y1, nullptr, nullptr, conv1_b, bn1_s, bn1_b, MTOK);
  // 7. depthwise 3x3 (2 tokens/thread) -> y2 bf16
  dwconv_kernel<<<B_ * 32 * 16, 192, 0, stream>>>(y1, w2s, Bc, y2);
  // 8. conv3 MFMA GEMM + bias/BN -> y3 fp32 AND out tokens (= x2 + y3)
  mgemm_kernel<GM_CONV3, 1536><<<dim3(128, 3), 256, 0, stream>>>(
      y2, wc316, y3, (float*)d_out, x2, conv3_b, bn3_s, bn3_b, MTOK);
  // 9. pool, 10. SE
  pool_kernel<<<dim3(B_, 16), 384, 0, stream>>>(y3, w0p);
  se_kernel<<<B_, 128, 0, stream>>>(w0p, comp_w, comp_b, exc_w, exc_b, wfin);
  // 11. cls rows of out
  clsfix_kernel<<<(B_ * C_ + 255) / 256, 256, 0, stream>>>(x2, cls, wfin, (float*)d_out);
}

// Round 3
// 414.599 us; speedup vs baseline: 1.0075x; 1.0075x over previous
//
#include <hip/hip_runtime.h>
#include <math.h>

#define DI __device__ __forceinline__

namespace {

constexpr int B_ = 16;
constexpr int N_ = 1025;
constexpr int C_ = 384;
constexpr int H_ = 6;
constexpr int HD_ = 64;
constexpr int HID_ = 1536;
constexpr int P_ = 1024;          // spatial tokens (32x32)
constexpr int MTOK = B_ * P_;     // 16384
constexpr int MALL = B_ * N_;     // 16400
constexpr int NPAD = 1088;        // padded key stride for V^T (16B-aligned rows)
constexpr long long AF = (long long)MALL * C_;  // 6297600 elems

// weight-conversion segment bounds (contiguous bf16 dst)
constexpr int NQKV = 3 * C_ * C_;     // 442368
constexpr int NPROJ = C_ * C_;        // 147456
constexpr int NC1 = HID_ * C_;        // 589824
constexpr int NC3 = C_ * HID_;        // 589824
constexpr int NW2 = HID_ * 9;         // 13824
constexpr int T1 = NQKV, T2 = T1 + NPROJ, T3 = T2 + NC1, T4 = T3 + NC3;
constexpr int T5 = T4 + NW2, T6 = T5 + HID_;

typedef __attribute__((ext_vector_type(4))) float f32x4;
typedef __attribute__((ext_vector_type(16))) float f32x16;
typedef __attribute__((ext_vector_type(8))) short bf16x8;

DI float gelu_f(float x) { return 0.5f * x * (1.0f + erff(x * 0.7071067811865475f)); }

DI float us2f(unsigned short u) {
  union { unsigned int i; float f; } c; c.i = ((unsigned)u) << 16; return c.f;
}
DI unsigned short f2us(float f) {
  union { float f; unsigned int i; } c; c.f = f;
  unsigned int r = c.i + 0x7FFF + ((c.i >> 16) & 1);
  return (unsigned short)(r >> 16);
}
DI unsigned short f2us_trunc(float f) {   // truncation: 1 shift, no round
  union { float f; unsigned int i; } c; c.f = f;
  return (unsigned short)(c.i >> 16);
}
DI void bf8_to_f(const uint4 v, float* f) {
  const unsigned int u[4] = {v.x, v.y, v.z, v.w};
#pragma unroll
  for (int t = 0; t < 4; t++) {
    union { unsigned int i; float fl; } lo, hi;
    lo.i = (u[t] & 0xffffu) << 16;
    hi.i = u[t] & 0xffff0000u;
    f[2 * t] = lo.fl; f[2 * t + 1] = hi.fl;
  }
}
DI uint4 f_to_bf8(const float* f) {
  unsigned int w[4];
#pragma unroll
  for (int t = 0; t < 4; t++)
    w[t] = (unsigned)f2us(f[2 * t]) | ((unsigned)f2us(f[2 * t + 1]) << 16);
  return make_uint4(w[0], w[1], w[2], w[3]);
}

// pack two f32 -> one dword of two bf16 (RNE), the T12 primitive
DI unsigned cvt_pk_bf16(float lo, float hi) {
  unsigned d;
  asm("v_cvt_pk_bf16_f32 %0, %1, %2" : "=v"(d) : "v"(lo), "v"(hi));
  return d;
}
// a.lanes32-63 <-> b.lanes0-31 exchange (see fattn fragment assembly)
DI void permswap(unsigned &a, unsigned &b) {
  asm("v_permlane32_swap_b32 %0, %1" : "+v"(a), "+v"(b));
}

// async global -> LDS, 16 B per lane (lane i lands at ldsbase + i*16)
DI void gl2lds16(const unsigned short* g, unsigned short* l) {
  __builtin_amdgcn_global_load_lds(
      (const __attribute__((address_space(1))) void*)g,
      (__attribute__((address_space(3))) void*)l, 16, 0, 0);
}

// ---------------- fused weight conversion / prep (one launch) ----------------
// dst16 layout (contiguous): [qkv | proj | conv1 | conv3 | w2s(tap-major, BN folded)]
__global__ __launch_bounds__(256) void cvtall_kernel(
    const float* __restrict__ qkv_w, const float* __restrict__ proj_w,
    const float* __restrict__ conv1_w, const float* __restrict__ conv3_w,
    const float* __restrict__ conv2_w, const float* __restrict__ c2b,
    const float* __restrict__ s2, const float* __restrict__ b2,
    unsigned short* __restrict__ dst16, float* __restrict__ Bc)
{
  const int idx = blockIdx.x * 256 + threadIdx.x;
  if (idx < T1)      dst16[idx] = f2us(qkv_w[idx]);
  else if (idx < T2) dst16[idx] = f2us(proj_w[idx - T1]);
  else if (idx < T3) dst16[idx] = f2us(conv1_w[idx - T2]);
  else if (idx < T4) dst16[idx] = f2us(conv3_w[idx - T3]);
  else if (idx < T5) {
    const int r = idx - T4, tap = r / HID_, c = r % HID_;
    dst16[idx] = f2us(conv2_w[c * 9 + tap] * s2[c]);
  } else if (idx < T6) {
    const int c = idx - T5;
    Bc[c] = c2b[c] * s2[c] + b2[c];
  }
}

// ---------------- LayerNorm, wave-per-row (no LDS, shfl reduce), bf16 out ----------------
__global__ __launch_bounds__(256) void lnw_kernel(
    const float* __restrict__ x, const float* __restrict__ g,
    const float* __restrict__ b, unsigned short* __restrict__ out,
    float* __restrict__ cls_out, int nrows)
{
  const int row = blockIdx.x * 4 + (threadIdx.x >> 6);   // wave-uniform
  if (row >= nrows) return;
  const int lane = threadIdx.x & 63;
  const float* xr = x + (long long)row * C_;
  float v[6];
#pragma unroll
  for (int i = 0; i < 6; i++) v[i] = xr[lane + 64 * i];
  float s = 0.f, q = 0.f;
#pragma unroll
  for (int i = 0; i < 6; i++) { s += v[i]; q += v[i] * v[i]; }
#pragma unroll
  for (int m = 1; m < 64; m <<= 1) {
    s += __shfl_xor(s, m, 64);
    q += __shfl_xor(q, m, 64);
  }
  const float mean = s * (1.0f / C_);
  const float var  = q * (1.0f / C_) - mean * mean;
  const float rstd = rsqrtf(var + 1e-5f);
  unsigned short* orow = out + (long long)row * C_;
  const bool iscls = (cls_out != nullptr) && (row % N_) == 0;
  float* cr = iscls ? cls_out + (long long)(row / N_) * C_ : nullptr;
#pragma unroll
  for (int i = 0; i < 6; i++) {
    const int c = lane + 64 * i;
    const float r = (v[i] - mean) * rstd * g[c] + b[c];
    orow[c] = f2us(r);
    if (iscls) cr[c] = r;
  }
}

// ---------------- V transpose: (bh,n,d) -> (bh,d,n) padded, zero-filled tail ----------------
__global__ __launch_bounds__(256) void vtrans_kernel(
    const unsigned short* __restrict__ v, unsigned short* __restrict__ vt)
{
  __shared__ unsigned short t[64][72];
  const int bh = blockIdx.x, nt = blockIdx.y;
  const int n0 = nt * 64;
  const int tid = threadIdx.x;
  {
    const int nl = tid >> 2;            // 0..63
    const int dc = (tid & 3) * 16;      // 0,16,32,48
    const int gn = n0 + nl;
    uint4 a = make_uint4(0u,0u,0u,0u), b = make_uint4(0u,0u,0u,0u);
    if (gn < N_) {
      const unsigned short* p = v + ((long long)bh * N_ + gn) * HD_ + dc;
      a = *(const uint4*)p; b = *(const uint4*)(p + 8);
    }
    *(uint4*)&t[nl][dc] = a;
    *(uint4*)&t[nl][dc + 8] = b;
  }
  __syncthreads();
  {
    const int dl = tid >> 2;            // 0..63
    const int nc = (tid & 3) * 16;
    unsigned short tmp[16];
#pragma unroll
    for (int i = 0; i < 16; i++) tmp[i] = t[nc + i][dl];
    unsigned short* p = vt + ((long long)bh * HD_ + dl) * NPAD + n0 + nc;
    *(uint4*)p = *(uint4*)&tmp[0];
    *(uint4*)(p + 8) = *(uint4*)&tmp[8];
  }
}

// ---------------- bf16 MFMA GEMM with global_load_lds staging ----------------
// CONV3 epilogue also writes out = x2 + y3 directly to d_out token rows
// (o1 = d_out, o2 = x2); y3 raw kept for the pool.
enum { GM_QKV = 0, GM_PROJ = 1, GM_CONV1 = 2, GM_CONV3 = 3 };

template <int MODE, int K>
__global__ __launch_bounds__(256) void mgemm_kernel(
    const unsigned short* __restrict__ A, const unsigned short* __restrict__ W,
    void* __restrict__ o0, void* __restrict__ o1, void* __restrict__ o2,
    const float* __restrict__ e0, const float* __restrict__ e1,
    const float* __restrict__ e2, int M)
{
  __shared__ unsigned short As[128][64];
  __shared__ unsigned short Bs[128][64];
  const int m0 = blockIdx.x * 128, n0 = blockIdx.y * 128;
  if (m0 >= M) return;   // grid padded to multiple-of-8 m-tiles
  const int tid = threadIdx.x;
  const int lane = tid & 63, wv = tid >> 6;
  const int lane15 = lane & 15, quad = lane >> 4;
  const int wm = (wv >> 1) * 64, wn = (wv & 1) * 64;

  const unsigned short* agp[4];
  const unsigned short* bgp[4];
#pragma unroll
  for (int t = 0; t < 4; t++) {
    const int lr = wv * 32 + t * 8 + (lane >> 3);
    const int chunk = (lane & 7) ^ (lr & 7);
    int gm = m0 + lr;
    if (gm > M - 1) gm = M - 1;                  // clamp; epilogue masks m>=M
    long long arow = gm;
    if constexpr (MODE == GM_CONV1) arow = (long long)(gm >> 10) * N_ + 1 + (gm & 1023);
    agp[t] = A + arow * K + chunk * 8;
    bgp[t] = W + (long long)(n0 + lr) * K + chunk * 8;
  }

  f32x4 acc[4][4];
#pragma unroll
  for (int i = 0; i < 4; i++)
#pragma unroll
    for (int j = 0; j < 4; j++) acc[i][j] = (f32x4)0.f;

  const int xsel = lane15 & 7;
  for (int k0 = 0; k0 < K; k0 += 64) {
    __syncthreads();
#pragma unroll
    for (int t = 0; t < 4; t++) {
      gl2lds16(agp[t] + k0, &As[wv * 32 + t * 8][0]);
      gl2lds16(bgp[t] + k0, &Bs[wv * 32 + t * 8][0]);
    }
    __syncthreads();
#pragma unroll
    for (int kh = 0; kh < 2; kh++) {
      bf16x8 af[4], bfr[4];
#pragma unroll
      for (int i = 0; i < 4; i++)
        af[i] = *(const bf16x8*)&As[wm + i * 16 + lane15][((kh * 4 + quad) ^ xsel) * 8];
#pragma unroll
      for (int j = 0; j < 4; j++)
        bfr[j] = *(const bf16x8*)&Bs[wn + j * 16 + lane15][((kh * 4 + quad) ^ xsel) * 8];
#pragma unroll
      for (int i = 0; i < 4; i++)
#pragma unroll
        for (int j = 0; j < 4; j++)
          acc[i][j] = __builtin_amdgcn_mfma_f32_16x16x32_bf16(af[i], bfr[j], acc[i][j], 0, 0, 0);
    }
  }
  // epilogue: C/D layout col=lane&15, row=quad*4+r
#pragma unroll
  for (int i = 0; i < 4; i++) {
#pragma unroll
    for (int r = 0; r < 4; r++) {
      const int m = m0 + wm + i * 16 + quad * 4 + r;
      if (m >= M) continue;
#pragma unroll
      for (int j = 0; j < 4; j++) {
        const int n = n0 + wn + j * 16 + lane15;
        const float val = acc[i][j][r];
        if constexpr (MODE == GM_QKV) {
          const int which = n / C_, rr = n % C_, hh = rr >> 6, e = rr & 63;
          const int b = m / N_, nn = m % N_;
          unsigned short* dst = (unsigned short*)((which == 0) ? o0 : ((which == 1) ? o1 : o2));
          // fold softmax scale AND log2(e) into Q (softmax uses exp2)
          const float sval = (which == 0) ? val * 0.18033688f : val;
          dst[(((long long)b * H_ + hh) * N_ + nn) * HD_ + e] = f2us(sval);
        } else if constexpr (MODE == GM_PROJ) {
          ((float*)o0)[(long long)m * C_ + n] = val + e0[(long long)m * C_ + n] + e1[n];
        } else if constexpr (MODE == GM_CONV1) {
          ((unsigned short*)o0)[(long long)m * HID_ + n] =
              f2us(gelu_f((val + e0[n]) * e1[n] + e2[n]));
        } else {  // GM_CONV3: y3 raw + fused residual out
          const float val2 = (val + e0[n]) * e1[n] + e2[n];
          ((float*)o0)[(long long)m * C_ + n] = val2;
          const int bb = m >> 10, pp = m & 1023;
          // x2 and out are both (b, 1+p, c) rows over N_=1025 — SAME index
          const long long orow = ((long long)bb * N_ + 1 + pp) * C_ + n;
          ((float*)o1)[orow] = ((const float*)o2)[orow] + val2;
        }
      }
    }
  }
}

// ---------------- Flash attention: 32x32x16, swapped QK^T, in-register softmax,
// SPLIT-K x2 (flash-decoding). 8 waves: kg = wv>>2 owns half the keys (kg0: 9
// tiles of 64, kg1: 8), qw = wv&3 owns 32 q-rows of the 128-q tile. The max-free
// exp2 softmax makes partials additive: merge = O_a+O_b, l_a+l_b via LDS overlay
// on the dead K/V buffers. Halves each wave's serial chain vs r2 (9 vs 17 iters)
// and doubles wave supply (6912 waves).
__global__ __launch_bounds__(512) void fattn_kernel(
    const unsigned short* __restrict__ q, const unsigned short* __restrict__ k,
    const unsigned short* __restrict__ vt, unsigned short* __restrict__ o)
{
  __shared__ unsigned short smem[32768];   // 64KB: K[(kg*2+buf)*4096] | V at +16384
  const int tid = threadIdx.x;
  const int lane = tid & 63, wv = tid >> 6;          // wv 0..7
  const int qw = wv & 3, kg = wv >> 2;
  const int lane31 = lane & 31, half = lane >> 5;
  const int x7 = lane & 7;
  const int bh = blockIdx.x, qt = blockIdx.y;
  const long long headoff = (long long)bh * N_;
  const int q0w = qt * 128 + qw * 32;
  const bool active = q0w < N_;            // wave-uniform; OOB waves only stage
  const int nreal = kg ? 8 : 9;            // tiles this k-group computes
  const int kbase = kg * 576;              // key offset of this k-group

  unsigned short* Ksm = smem;              // K tiles
  unsigned short* Vsm = smem + 16384;      // V^T tiles

  // Q fragments: lane holds Q[q=lane31][d = m*16 + half*8 + j]
  int gq = q0w + lane31; if (gq > N_ - 1) gq = N_ - 1;
  const unsigned short* qp = q + (headoff + gq) * HD_ + half * 8;
  bf16x8 qf[4];
#pragma unroll
  for (int m = 0; m < 4; m++) qf[m] = *(const bf16x8*)(qp + m * 16);

  // staging: per wave 2 issues per array per tile; issue t covers rows
  // t*32 + qw*8 + (lane>>3) of this kg's tile
  const unsigned short* kgp[2];
  const unsigned short* vgp[2];
#pragma unroll
  for (int t = 0; t < 2; t++) {
    const int r = t * 32 + qw * 8 + (lane >> 3);
    const int ch = (lane & 7) ^ (r & 7);
    kgp[t] = k + (headoff + kbase + r) * HD_ + ch * 8;
    vgp[t] = vt + ((long long)bh * HD_ + r) * NPAD + kbase + ch * 8;
  }

  f32x16 O0 = (f32x16)0.f, O1 = (f32x16)0.f;   // O[q=crow(r,half)][d=lane31+db*32]
  float l = 0.f;

  // prologue: stage this kg's tile 0 into buffer 0
#pragma unroll
  for (int t = 0; t < 2; t++) {
    gl2lds16(kgp[t], Ksm + (kg * 2 + 0) * 4096 + (t * 32 + qw * 8) * 64);
    gl2lds16(vgp[t], Vsm + (kg * 2 + 0) * 4096 + (t * 32 + qw * 8) * 64);
  }
  __syncthreads();

  for (int it = 0; it < 9; it++) {
    const int cur = it & 1;
    if (it + 1 < nreal) {
      const long long koff = (long long)(it + 1) * 64;
#pragma unroll
      for (int t = 0; t < 2; t++) {
        gl2lds16(kgp[t] + koff * HD_,
                 Ksm + (kg * 2 + (cur ^ 1)) * 4096 + (t * 32 + qw * 8) * 64);
        gl2lds16(vgp[t] + koff,
                 Vsm + (kg * 2 + (cur ^ 1)) * 4096 + (t * 32 + qw * 8) * 64);
      }
    }
    if (active && it < nreal) {
      const unsigned short* Kb = Ksm + (kg * 2 + cur) * 4096;
      const unsigned short* Vb = Vsm + (kg * 2 + cur) * 4096;
      // S^T = K Q^T  (log2e and 1/8 scale pre-folded into Q)
      f32x16 S0 = (f32x16)0.f, S1 = (f32x16)0.f;
      __builtin_amdgcn_s_setprio(1);
#pragma unroll
      for (int m = 0; m < 4; m++) {
        const int chs = ((m * 2 + half) ^ x7) * 8;
        const bf16x8 k0 = *(const bf16x8*)&Kb[lane31 * 64 + chs];
        const bf16x8 k1 = *(const bf16x8*)&Kb[(32 + lane31) * 64 + chs];
        S0 = __builtin_amdgcn_mfma_f32_32x32x16_bf16(k0, qf[m], S0, 0, 0, 0);
        S1 = __builtin_amdgcn_mfma_f32_32x32x16_bf16(k1, qf[m], S1, 0, 0, 0);
      }
      __builtin_amdgcn_s_setprio(0);
      if (kg == 1 && it == 7) {            // keys 1024..1087: mask OOB
#pragma unroll
        for (int r = 0; r < 16; r++) {
          const int kl = (r & 3) + 8 * (r >> 2) + 4 * half;
          if (1024 + kl >= N_) S0[r] = -1e30f;
          S1[r] = -1e30f;
        }
      }
      // P = 2^S in-register; pack pairs (k even,k odd) -> bf16 dwords
      unsigned pk0[8], pk1[8];
#pragma unroll
      for (int s = 0; s < 8; s++) {
        const float a0 = exp2f(S0[2 * s]), a1 = exp2f(S0[2 * s + 1]);
        const float b0 = exp2f(S1[2 * s]), b1 = exp2f(S1[2 * s + 1]);
        l += (a0 + a1) + (b0 + b1);
        pk0[s] = cvt_pk_bf16(a0, a1);
        pk1[s] = cvt_pk_bf16(b0, b1);
      }
      // assemble PV A-fragments via permlane32_swap (4 swaps per 32k-block)
      unsigned wkc[4][4];
#pragma unroll
      for (int bb = 0; bb < 2; bb++) {
#pragma unroll
        for (int kc2 = 0; kc2 < 2; kc2++) {
          unsigned a0 = bb ? pk1[kc2 * 4 + 0] : pk0[kc2 * 4 + 0];
          unsigned a2 = bb ? pk1[kc2 * 4 + 2] : pk0[kc2 * 4 + 2];
          permswap(a0, a2);
          unsigned a1 = bb ? pk1[kc2 * 4 + 1] : pk0[kc2 * 4 + 1];
          unsigned a3 = bb ? pk1[kc2 * 4 + 3] : pk0[kc2 * 4 + 3];
          permswap(a1, a3);
          const int kc = bb * 2 + kc2;
          wkc[kc][0] = a0; wkc[kc][1] = a1; wkc[kc][2] = a2; wkc[kc][3] = a3;
        }
      }
      // O += P V  (B-frag from Vt: V[k][d] = Vt[d][k], d=lane31+db*32)
      __builtin_amdgcn_s_setprio(1);
#pragma unroll
      for (int kc = 0; kc < 4; kc++) {
        union { unsigned u[4]; bf16x8 v; } pa;
        pa.u[0] = wkc[kc][0]; pa.u[1] = wkc[kc][1];
        pa.u[2] = wkc[kc][2]; pa.u[3] = wkc[kc][3];
        const int chv = ((kc * 2 + half) ^ x7) * 8;
        const bf16x8 v0 = *(const bf16x8*)&Vb[lane31 * 64 + chv];
        const bf16x8 v1 = *(const bf16x8*)&Vb[(32 + lane31) * 64 + chv];
        O0 = __builtin_amdgcn_mfma_f32_32x32x16_bf16(pa.v, v0, O0, 0, 0, 0);
        O1 = __builtin_amdgcn_mfma_f32_32x32x16_bf16(pa.v, v1, O1, 0, 0, 0);
      }
      __builtin_amdgcn_s_setprio(0);
    }
    // one barrier per tile: drains own async loads AND guards buffer reuse
    __syncthreads();
  }

  // ---- split-K merge: kg1 writes partial O,l; kg0 adds (LDS buffers dead) ----
  float* mrg = (float*)smem;               // [qw][33][64] f32 = 33792 B
  if (kg == 1 && active) {
    float* mq = mrg + qw * 33 * 64 + lane;
#pragma unroll
    for (int j = 0; j < 16; j++) mq[j * 64] = O0[j];
#pragma unroll
    for (int j = 0; j < 16; j++) mq[(16 + j) * 64] = O1[j];
    mq[32 * 64] = l;
  }
  __syncthreads();
  if (kg == 0 && active) {
    float* mq = mrg + qw * 33 * 64 + lane;
#pragma unroll
    for (int j = 0; j < 16; j++) O0[j] += mq[j * 64];
#pragma unroll
    for (int j = 0; j < 16; j++) O1[j] += mq[(16 + j) * 64];
    l += mq[32 * 64];

    // merge halves of l, redistribute 1/l to output rows
    l += __shfl_xor(l, 32, 64);
    const float rinv = 1.0f / l;
    float li[16];
#pragma unroll
    for (int r = 0; r < 16; r++) {
      const int qloc = (r & 3) + 8 * (r >> 2) + 4 * half;
      li[r] = __int_as_float(
          __builtin_amdgcn_ds_bpermute(qloc * 4, __float_as_int(rinv)));
    }
    const int b = bh / H_, hh = bh % H_;
#pragma unroll
    for (int r = 0; r < 16; r++) {
      const int qloc = (r & 3) + 8 * (r >> 2) + 4 * half;
      const int gqr = q0w + qloc;
      if (gqr < N_) {
        const long long orow = ((long long)b * N_ + gqr) * C_ + hh * HD_;
        o[orow + lane31] = f2us(O0[r] * li[r]);
        o[orow + 32 + lane31] = f2us(O1[r] * li[r]);
      }
    }
  }
}

// ---------------- Depthwise 3x3, 2 tokens/thread sliding window ----------------
// block = (b, i, j-pair); 192 threads each own 8 channels for both j0=2jp, j1=2jp+1.
// 12 uint4 data loads cover both outputs; weights unpacked once; shortcut = center taps.
__global__ __launch_bounds__(192) void dwconv_kernel(
    const unsigned short* __restrict__ y1, const unsigned short* __restrict__ w2s,
    const float* __restrict__ Bc, unsigned short* __restrict__ y2)
{
  const int jp = blockIdx.x & 15;
  const int i  = (blockIdx.x >> 4) & 31;
  const int b  = blockIdx.x >> 9;
  const int j0 = jp * 2;
  const int cb = threadIdx.x << 3;

  float wf[9][8];
#pragma unroll
  for (int tap = 0; tap < 9; tap++) {
    const uint4 wv = *(const uint4*)(w2s + tap * HID_ + cb);
    bf8_to_f(wv, wf[tap]);
  }
  float acc0[8] = {}, acc1[8] = {};
  float sh0[8], sh1[8];
#pragma unroll
  for (int di = -1; di <= 1; di++) {
    const int ii = i + di;
    if (ii < 0 || ii > 31) continue;
    const long long rowbase = ((long long)b * P_ + ii * 32) * HID_ + cb;
#pragma unroll
    for (int dj = -1; dj <= 2; dj++) {
      const int jj = j0 + dj;
      if (jj < 0 || jj > 31) continue;
      const uint4 dv = *(const uint4*)(y1 + rowbase + (long long)jj * HID_);
      float df[8]; bf8_to_f(dv, df);
      if (dj <= 1) {
        const int tap = (di + 1) * 3 + (dj + 1);
#pragma unroll
        for (int t = 0; t < 8; t++) acc0[t] += df[t] * wf[tap][t];
      }
      if (dj >= 0) {
        const int tap = (di + 1) * 3 + dj;
#pragma unroll
        for (int t = 0; t < 8; t++) acc1[t] += df[t] * wf[tap][t];
      }
      if (di == 0 && dj == 0) {
#pragma unroll
        for (int t = 0; t < 8; t++) sh0[t] = df[t];
      }
      if (di == 0 && dj == 1) {
#pragma unroll
        for (int t = 0; t < 8; t++) sh1[t] = df[t];
      }
    }
  }
  const float4 bc0 = *(const float4*)(Bc + cb);
  const float4 bc1 = *(const float4*)(Bc + cb + 4);
  const float bcv[8] = {bc0.x, bc0.y, bc0.z, bc0.w, bc1.x, bc1.y, bc1.z, bc1.w};
  float of0[8], of1[8];
#pragma unroll
  for (int t = 0; t < 8; t++) {
    of0[t] = sh0[t] + gelu_f(acc0[t] + bcv[t]);
    of1[t] = sh1[t] + gelu_f(acc1[t] + bcv[t]);
  }
  const long long tok0 = ((long long)b * P_ + i * 32 + j0) * HID_ + cb;
  *(uint4*)(y2 + tok0) = f_to_bf8(of0);
  *(uint4*)(y2 + tok0 + HID_) = f_to_bf8(of1);
}

// ---------------- Spatial pooling (two-stage, no atomics) ----------------
__global__ __launch_bounds__(384) void pool_kernel(const float* __restrict__ y3,
                                                   float* __restrict__ w0p)
{
  const int b = blockIdx.x, chunk = blockIdx.y;
  const int c = threadIdx.x;
  float s = 0.f;
  for (int p = chunk * 64; p < chunk * 64 + 64; p++)
    s += y3[((long long)b * P_ + p) * C_ + c];
  w0p[((long long)b * 16 + chunk) * C_ + c] = s;
}

// ---------------- Squeeze-excite MLP ----------------
__global__ __launch_bounds__(128) void se_kernel(
    const float* __restrict__ w0p, const float* __restrict__ cw,
    const float* __restrict__ cb, const float* __restrict__ ew,
    const float* __restrict__ eb, float* __restrict__ wfin)
{
  __shared__ float wm[384];
  __shared__ float t1[96];
  const int b = blockIdx.x, t = threadIdx.x;
  for (int c = t; c < 384; c += 128) {
    float s = 0.f;
    for (int ch = 0; ch < 16; ch++) s += w0p[((long long)b * 16 + ch) * C_ + c];
    wm[c] = s * (1.0f / 1024.0f);
  }
  __syncthreads();
  if (t < 96) {
    float s = cb[t];
    for (int c = 0; c < 384; c++) s += wm[c] * cw[t * 384 + c];
    t1[t] = gelu_f(s);
  }
  __syncthreads();
  for (int c = t; c < 384; c += 128) {
    float s = eb[c];
    for (int j = 0; j < 96; j++) s += t1[j] * ew[c * 96 + j];
    wfin[(long long)b * C_ + c] = s;
  }
}

// ---------------- cls rows: out[b,0,:] = x2[b,0,:] + cls*wfin ----------------
__global__ __launch_bounds__(256) void clsfix_kernel(
    const float* __restrict__ x2, const float* __restrict__ cls,
    const float* __restrict__ wfin, float* __restrict__ out)
{
  const int idx = blockIdx.x * 256 + threadIdx.x;
  if (idx >= B_ * C_) return;
  const int b = idx / C_, c = idx % C_;
  const long long row = (long long)b * N_ * C_ + c;
  out[row] = x2[row] + cls[idx] * wfin[idx];
}

}  // namespace

// Workspace layout (bytes), total ~130 MiB:
//   RegionA [0, 50331648):            q,k,v bf16 -> h2 bf16 -> y2 bf16
//   RegionB [50331648, 100663296):    h bf16 -> o_mat bf16 -> y1 bf16 -> y3 fp32
//   RegionC [100663296, 125853696):   vT bf16 (during attention) -> x2 fp32
//   tail:                             bf16 weights(contig)+w2s, Bc, cls, w0p, wfin
extern "C" void kernel_launch(void* const* d_in, const int* in_sizes, int n_in,
                              void* d_out, int out_size, void* d_ws, size_t ws_size,
                              hipStream_t stream)
{
  const float* x       = (const float*)d_in[0];
  const float* ln1_g   = (const float*)d_in[1];
  const float* ln1_b   = (const float*)d_in[2];
  const float* qkv_w   = (const float*)d_in[3];
  const float* proj_w  = (const float*)d_in[4];
  const float* proj_b  = (const float*)d_in[5];
  const float* ln2_g   = (const float*)d_in[6];
  const float* ln2_b   = (const float*)d_in[7];
  const float* conv1_w = (const float*)d_in[8];
  const float* conv1_b = (const float*)d_in[9];
  const float* conv2_w = (const float*)d_in[10];
  const float* conv2_b = (const float*)d_in[11];
  const float* conv3_w = (const float*)d_in[12];
  const float* conv3_b = (const float*)d_in[13];
  const float* bn1_s   = (const float*)d_in[14];
  const float* bn1_b   = (const float*)d_in[15];
  const float* bn2_s   = (const float*)d_in[16];
  const float* bn2_b   = (const float*)d_in[17];
  const float* bn3_s   = (const float*)d_in[18];
  const float* bn3_b   = (const float*)d_in[19];
  const float* comp_w  = (const float*)d_in[20];
  const float* comp_b  = (const float*)d_in[21];
  const float* exc_w   = (const float*)d_in[22];
  const float* exc_b   = (const float*)d_in[23];

  char* wsb = (char*)d_ws;
  const size_t RA = 50331648, RB = 50331648, RC = 25190400;
  const size_t tailbytes = (size_t)T5 * 2 +
                           (size_t)(HID_ + B_ * C_ + B_ * 16 * C_ + B_ * C_) * 4;
  const size_t needed = RA + RB + RC + tailbytes;
  if (ws_size < needed) return;

  unsigned short* qb  = (unsigned short*)wsb;
  unsigned short* kb  = qb + AF;
  unsigned short* vb  = kb + AF;
  unsigned short* h2b = (unsigned short*)wsb;          // overlay RA
  unsigned short* y2  = (unsigned short*)wsb;          // overlay RA
  char* rb = wsb + RA;
  unsigned short* hb  = (unsigned short*)rb;           // LN1 out
  unsigned short* o16 = (unsigned short*)rb;           // attn out (overlay)
  unsigned short* y1  = (unsigned short*)rb;           // conv1 out (overlay)
  float* y3           = (float*)rb;                    // conv3 out (overlay)
  unsigned short* vtb = (unsigned short*)(wsb + RA + RB);  // V^T (overlay RC)
  float* x2 = (float*)(wsb + RA + RB);                     // x2 after attention
  unsigned short* w16 = (unsigned short*)(wsb + RA + RB + RC);  // contiguous weights
  unsigned short* wqkv16  = w16;
  unsigned short* wproj16 = w16 + T1;
  unsigned short* wc116   = w16 + T2;
  unsigned short* wc316   = w16 + T3;
  unsigned short* w2s     = w16 + T4;
  float* Bc   = (float*)(w16 + T5);
  float* cls  = Bc + HID_;
  float* w0p  = cls + B_ * C_;
  float* wfin = w0p + B_ * 16 * C_;

  // 0. fused weight conversion / prep (1 launch)
  cvtall_kernel<<<(T6 + 255) / 256, 256, 0, stream>>>(
      qkv_w, proj_w, conv1_w, conv3_w, conv2_w, conv2_b, bn2_s, bn2_b, w16, Bc);
  // 1. LN1 -> bf16 (wave-per-row)
  lnw_kernel<<<(MALL + 3) / 4, 256, 0, stream>>>(x, ln1_g, ln1_b, hb, nullptr, MALL);
  // 2. QKV MFMA GEMM (Q pre-scaled by 0.125*log2e)
  mgemm_kernel<GM_QKV, 384><<<dim3(136, 9), 256, 0, stream>>>(
      hb, wqkv16, qb, kb, vb, nullptr, nullptr, nullptr, MALL);
  // 2b. V transpose -> vT (bh, d, n) padded
  vtrans_kernel<<<dim3(B_ * H_, 17), 256, 0, stream>>>(vb, vtb);
  // 3. Flash attention (32x32 swapped-QK^T, in-register softmax, split-K x2)
  fattn_kernel<<<dim3(B_ * H_, 9), 512, 0, stream>>>(qb, kb, vtb, o16);
  // 4. proj MFMA GEMM + residual -> x2 fp32 (overwrites vT region)
  mgemm_kernel<GM_PROJ, 384><<<dim3(136, 3), 256, 0, stream>>>(
      o16, wproj16, x2, nullptr, nullptr, x, proj_b, nullptr, MALL);
  // 5. LN2 -> bf16 h2 (+ fp32 cls rows)
  lnw_kernel<<<(MALL + 3) / 4, 256, 0, stream>>>(x2, ln2_g, ln2_b, h2b, cls, MALL);
  // 6. conv1 MFMA GEMM + bias/BN/GELU -> y1 bf16
  mgemm_kernel<GM_CONV1, 384><<<dim3(128, 12), 256, 0, stream>>>(
      h2b, wc116, y1, nullptr, nullptr, conv1_b, bn1_s, bn1_b, MTOK);
  // 7. depthwise 3x3 (2 tokens/thread) -> y2 bf16
  dwconv_kernel<<<B_ * 32 * 16, 192, 0, stream>>>(y1, w2s, Bc, y2);
  // 8. conv3 MFMA GEMM + bias/BN -> y3 fp32 AND out tokens (= x2 + y3)
  mgemm_kernel<GM_CONV3, 1536><<<dim3(128, 3), 256, 0, stream>>>(
      y2, wc316, y3, (float*)d_out, x2, conv3_b, bn3_s, bn3_b, MTOK);
  // 9. pool, 10. SE
  pool_kernel<<<dim3(B_, 16), 384, 0, stream>>>(y3, w0p);
  se_kernel<<<B_, 128, 0, stream>>>(w0p, comp_w, comp_b, exc_w, exc_b, wfin);
  // 11. cls rows of out
  clsfix_kernel<<<(B_ * C_ + 255) / 256, 256, 0, stream>>>(x2, cls, wfin, (float*)d_out);
}

// Round 4
// 406.067 us; speedup vs baseline: 1.0286x; 1.0210x over previous
//
#include <hip/hip_runtime.h>
#include <math.h>

#define DI __device__ __forceinline__

namespace {

constexpr int B_ = 16;
constexpr int N_ = 1025;
constexpr int C_ = 384;
constexpr int H_ = 6;
constexpr int HD_ = 64;
constexpr int HID_ = 1536;
constexpr int P_ = 1024;          // spatial tokens (32x32)
constexpr int MTOK = B_ * P_;     // 16384
constexpr int MALL = B_ * N_;     // 16400
constexpr int NPAD = 1088;        // padded key stride for V^T (16B-aligned rows)
constexpr long long AF = (long long)MALL * C_;  // 6297600 elems

// weight-conversion segment bounds (contiguous bf16 dst)
constexpr int NQKV = 3 * C_ * C_;     // 442368
constexpr int NPROJ = C_ * C_;        // 147456
constexpr int NC1 = HID_ * C_;        // 589824
constexpr int NC3 = C_ * HID_;        // 589824
constexpr int NW2 = HID_ * 9;         // 13824
constexpr int T1 = NQKV, T2 = T1 + NPROJ, T3 = T2 + NC1, T4 = T3 + NC3;
constexpr int T5 = T4 + NW2, T6 = T5 + HID_;

typedef __attribute__((ext_vector_type(4))) float f32x4;
typedef __attribute__((ext_vector_type(16))) float f32x16;
typedef __attribute__((ext_vector_type(8))) short bf16x8;

DI float gelu_f(float x) { return 0.5f * x * (1.0f + erff(x * 0.7071067811865475f)); }

DI float us2f(unsigned short u) {
  union { unsigned int i; float f; } c; c.i = ((unsigned)u) << 16; return c.f;
}
DI unsigned short f2us(float f) {
  union { float f; unsigned int i; } c; c.f = f;
  unsigned int r = c.i + 0x7FFF + ((c.i >> 16) & 1);
  return (unsigned short)(r >> 16);
}
DI unsigned short f2us_trunc(float f) {   // truncation: 1 shift, no round
  union { float f; unsigned int i; } c; c.f = f;
  return (unsigned short)(c.i >> 16);
}
DI void bf8_to_f(const uint4 v, float* f) {
  const unsigned int u[4] = {v.x, v.y, v.z, v.w};
#pragma unroll
  for (int t = 0; t < 4; t++) {
    union { unsigned int i; float fl; } lo, hi;
    lo.i = (u[t] & 0xffffu) << 16;
    hi.i = u[t] & 0xffff0000u;
    f[2 * t] = lo.fl; f[2 * t + 1] = hi.fl;
  }
}
DI uint4 f_to_bf8(const float* f) {
  unsigned int w[4];
#pragma unroll
  for (int t = 0; t < 4; t++)
    w[t] = (unsigned)f2us(f[2 * t]) | ((unsigned)f2us(f[2 * t + 1]) << 16);
  return make_uint4(w[0], w[1], w[2], w[3]);
}

// pack two f32 -> one dword of two bf16 (RNE), the T12 primitive
DI unsigned cvt_pk_bf16(float lo, float hi) {
  unsigned d;
  asm("v_cvt_pk_bf16_f32 %0, %1, %2" : "=v"(d) : "v"(lo), "v"(hi));
  return d;
}
// a.lanes32-63 <-> b.lanes0-31 exchange (see fattn fragment assembly)
DI void permswap(unsigned &a, unsigned &b) {
  asm("v_permlane32_swap_b32 %0, %1" : "+v"(a), "+v"(b));
}

// async global -> LDS, 16 B per lane (lane i lands at ldsbase + i*16)
DI void gl2lds16(const unsigned short* g, unsigned short* l) {
  __builtin_amdgcn_global_load_lds(
      (const __attribute__((address_space(1))) void*)g,
      (__attribute__((address_space(3))) void*)l, 16, 0, 0);
}

// ---------------- fused weight conversion / prep (one launch) ----------------
// dst16 layout (contiguous): [qkv | proj | conv1 | conv3 | w2s(tap-major, BN folded)]
__global__ __launch_bounds__(256) void cvtall_kernel(
    const float* __restrict__ qkv_w, const float* __restrict__ proj_w,
    const float* __restrict__ conv1_w, const float* __restrict__ conv3_w,
    const float* __restrict__ conv2_w, const float* __restrict__ c2b,
    const float* __restrict__ s2, const float* __restrict__ b2,
    unsigned short* __restrict__ dst16, float* __restrict__ Bc)
{
  const int idx = blockIdx.x * 256 + threadIdx.x;
  if (idx < T1)      dst16[idx] = f2us(qkv_w[idx]);
  else if (idx < T2) dst16[idx] = f2us(proj_w[idx - T1]);
  else if (idx < T3) dst16[idx] = f2us(conv1_w[idx - T2]);
  else if (idx < T4) dst16[idx] = f2us(conv3_w[idx - T3]);
  else if (idx < T5) {
    const int r = idx - T4, tap = r / HID_, c = r % HID_;
    dst16[idx] = f2us(conv2_w[c * 9 + tap] * s2[c]);
  } else if (idx < T6) {
    const int c = idx - T5;
    Bc[c] = c2b[c] * s2[c] + b2[c];
  }
}

// ---------------- LayerNorm, wave-per-row (no LDS, shfl reduce), bf16 out ----------------
__global__ __launch_bounds__(256) void lnw_kernel(
    const float* __restrict__ x, const float* __restrict__ g,
    const float* __restrict__ b, unsigned short* __restrict__ out,
    float* __restrict__ cls_out, int nrows)
{
  const int row = blockIdx.x * 4 + (threadIdx.x >> 6);   // wave-uniform
  if (row >= nrows) return;
  const int lane = threadIdx.x & 63;
  const float* xr = x + (long long)row * C_;
  float v[6];
#pragma unroll
  for (int i = 0; i < 6; i++) v[i] = xr[lane + 64 * i];
  float s = 0.f, q = 0.f;
#pragma unroll
  for (int i = 0; i < 6; i++) { s += v[i]; q += v[i] * v[i]; }
#pragma unroll
  for (int m = 1; m < 64; m <<= 1) {
    s += __shfl_xor(s, m, 64);
    q += __shfl_xor(q, m, 64);
  }
  const float mean = s * (1.0f / C_);
  const float var  = q * (1.0f / C_) - mean * mean;
  const float rstd = rsqrtf(var + 1e-5f);
  unsigned short* orow = out + (long long)row * C_;
  const bool iscls = (cls_out != nullptr) && (row % N_) == 0;
  float* cr = iscls ? cls_out + (long long)(row / N_) * C_ : nullptr;
#pragma unroll
  for (int i = 0; i < 6; i++) {
    const int c = lane + 64 * i;
    const float r = (v[i] - mean) * rstd * g[c] + b[c];
    orow[c] = f2us(r);
    if (iscls) cr[c] = r;
  }
}

// ---------------- V transpose: (bh,n,d) -> (bh,d,n) padded, zero-filled tail ----------------
__global__ __launch_bounds__(256) void vtrans_kernel(
    const unsigned short* __restrict__ v, unsigned short* __restrict__ vt)
{
  __shared__ unsigned short t[64][72];
  const int bh = blockIdx.x, nt = blockIdx.y;
  const int n0 = nt * 64;
  const int tid = threadIdx.x;
  {
    const int nl = tid >> 2;            // 0..63
    const int dc = (tid & 3) * 16;      // 0,16,32,48
    const int gn = n0 + nl;
    uint4 a = make_uint4(0u,0u,0u,0u), b = make_uint4(0u,0u,0u,0u);
    if (gn < N_) {
      const unsigned short* p = v + ((long long)bh * N_ + gn) * HD_ + dc;
      a = *(const uint4*)p; b = *(const uint4*)(p + 8);
    }
    *(uint4*)&t[nl][dc] = a;
    *(uint4*)&t[nl][dc + 8] = b;
  }
  __syncthreads();
  {
    const int dl = tid >> 2;            // 0..63
    const int nc = (tid & 3) * 16;
    unsigned short tmp[16];
#pragma unroll
    for (int i = 0; i < 16; i++) tmp[i] = t[nc + i][dl];
    unsigned short* p = vt + ((long long)bh * HD_ + dl) * NPAD + n0 + nc;
    *(uint4*)p = *(uint4*)&tmp[0];
    *(uint4*)(p + 8) = *(uint4*)&tmp[8];
  }
}

// ---------------- bf16 MFMA GEMM, double-buffered LDS + counted vmcnt (T3/T4) -
// Prefetch k-step t+1 into buf^1 while computing buf; raw s_barrier with
// s_waitcnt vmcnt(8) keeps the 8 prefetch loads in flight ACROSS the barrier
// (never drain to 0 in-loop). CONV3 epilogue also writes out = x2 + y3 directly.
enum { GM_QKV = 0, GM_PROJ = 1, GM_CONV1 = 2, GM_CONV3 = 3 };

template <int MODE, int K>
__global__ __launch_bounds__(256) void mgemm_kernel(
    const unsigned short* __restrict__ A, const unsigned short* __restrict__ W,
    void* __restrict__ o0, void* __restrict__ o1, void* __restrict__ o2,
    const float* __restrict__ e0, const float* __restrict__ e1,
    const float* __restrict__ e2, int M)
{
  __shared__ unsigned short As[2][128][64];
  __shared__ unsigned short Bs[2][128][64];
  const int m0 = blockIdx.x * 128, n0 = blockIdx.y * 128;
  if (m0 >= M) return;   // grid padded; block-uniform exit (no barrier hazard)
  const int tid = threadIdx.x;
  const int lane = tid & 63, wv = tid >> 6;
  const int lane15 = lane & 15, quad = lane >> 4;
  const int wm = (wv >> 1) * 64, wn = (wv & 1) * 64;

  const unsigned short* agp[4];
  const unsigned short* bgp[4];
#pragma unroll
  for (int t = 0; t < 4; t++) {
    const int lr = wv * 32 + t * 8 + (lane >> 3);
    const int chunk = (lane & 7) ^ (lr & 7);
    int gm = m0 + lr;
    if (gm > M - 1) gm = M - 1;                  // clamp; epilogue masks m>=M
    long long arow = gm;
    if constexpr (MODE == GM_CONV1) arow = (long long)(gm >> 10) * N_ + 1 + (gm & 1023);
    agp[t] = A + arow * K + chunk * 8;
    bgp[t] = W + (long long)(n0 + lr) * K + chunk * 8;
  }

  f32x4 acc[4][4];
#pragma unroll
  for (int i = 0; i < 4; i++)
#pragma unroll
    for (int j = 0; j < 4; j++) acc[i][j] = (f32x4)0.f;

  const int xsel = lane15 & 7;
  constexpr int NT = K / 64;

  // prologue: stage k-step 0 into buffer 0
#pragma unroll
  for (int t = 0; t < 4; t++) {
    gl2lds16(agp[t], &As[0][wv * 32 + t * 8][0]);
    gl2lds16(bgp[t], &Bs[0][wv * 32 + t * 8][0]);
  }

  for (int it = 0; it < NT; ++it) {
    const int cur = it & 1;
    if (it + 1 < NT) {
      const int k0 = (it + 1) * 64;
#pragma unroll
      for (int t = 0; t < 4; t++) {
        gl2lds16(agp[t] + k0, &As[cur ^ 1][wv * 32 + t * 8][0]);
        gl2lds16(bgp[t] + k0, &Bs[cur ^ 1][wv * 32 + t * 8][0]);
      }
      // wait only for the PREVIOUS step's 8 loads; keep the new 8 in flight
      asm volatile("s_waitcnt vmcnt(8)" ::: "memory");
    } else {
      asm volatile("s_waitcnt vmcnt(0)" ::: "memory");
    }
    asm volatile("s_barrier" ::: "memory");     // entry gate: cur fully staged
    __builtin_amdgcn_sched_barrier(0);
#pragma unroll
    for (int kh = 0; kh < 2; kh++) {
      bf16x8 af[4], bfr[4];
#pragma unroll
      for (int i = 0; i < 4; i++)
        af[i] = *(const bf16x8*)&As[cur][wm + i * 16 + lane15][((kh * 4 + quad) ^ xsel) * 8];
#pragma unroll
      for (int j = 0; j < 4; j++)
        bfr[j] = *(const bf16x8*)&Bs[cur][wn + j * 16 + lane15][((kh * 4 + quad) ^ xsel) * 8];
#pragma unroll
      for (int i = 0; i < 4; i++)
#pragma unroll
        for (int j = 0; j < 4; j++)
          acc[i][j] = __builtin_amdgcn_mfma_f32_16x16x32_bf16(af[i], bfr[j], acc[i][j], 0, 0, 0);
    }
    // exit gate: all waves done reading cur before next iter's issue overwrites
    asm volatile("s_barrier" ::: "memory");
  }
  // epilogue: C/D layout col=lane&15, row=quad*4+r
#pragma unroll
  for (int i = 0; i < 4; i++) {
#pragma unroll
    for (int r = 0; r < 4; r++) {
      const int m = m0 + wm + i * 16 + quad * 4 + r;
      if (m >= M) continue;
#pragma unroll
      for (int j = 0; j < 4; j++) {
        const int n = n0 + wn + j * 16 + lane15;
        const float val = acc[i][j][r];
        if constexpr (MODE == GM_QKV) {
          const int which = n / C_, rr = n % C_, hh = rr >> 6, e = rr & 63;
          const int b = m / N_, nn = m % N_;
          unsigned short* dst = (unsigned short*)((which == 0) ? o0 : ((which == 1) ? o1 : o2));
          // fold softmax scale AND log2(e) into Q (softmax uses exp2)
          const float sval = (which == 0) ? val * 0.18033688f : val;
          dst[(((long long)b * H_ + hh) * N_ + nn) * HD_ + e] = f2us(sval);
        } else if constexpr (MODE == GM_PROJ) {
          ((float*)o0)[(long long)m * C_ + n] = val + e0[(long long)m * C_ + n] + e1[n];
        } else if constexpr (MODE == GM_CONV1) {
          ((unsigned short*)o0)[(long long)m * HID_ + n] =
              f2us(gelu_f((val + e0[n]) * e1[n] + e2[n]));
        } else {  // GM_CONV3: y3 raw + fused residual out
          const float val2 = (val + e0[n]) * e1[n] + e2[n];
          ((float*)o0)[(long long)m * C_ + n] = val2;
          const int bb = m >> 10, pp = m & 1023;
          // x2 and out are both (b, 1+p, c) rows over N_=1025 — SAME index
          const long long orow = ((long long)bb * N_ + 1 + pp) * C_ + n;
          ((float*)o1)[orow] = ((const float*)o2)[orow] + val2;
        }
      }
    }
  }
}

// ---------------- Flash attention: 32x32x16, swapped QK^T, in-register softmax,
// SPLIT-K x2 (flash-decoding). 8 waves: kg = wv>>2 owns half the keys (kg0: 9
// tiles of 64, kg1: 8), qw = wv&3 owns 32 q-rows of the 128-q tile. The max-free
// exp2 softmax makes partials additive: merge = O_a+O_b, l_a+l_b via LDS overlay
// on the dead K/V buffers.
__global__ __launch_bounds__(512) void fattn_kernel(
    const unsigned short* __restrict__ q, const unsigned short* __restrict__ k,
    const unsigned short* __restrict__ vt, unsigned short* __restrict__ o)
{
  __shared__ unsigned short smem[32768];   // 64KB: K[(kg*2+buf)*4096] | V at +16384
  const int tid = threadIdx.x;
  const int lane = tid & 63, wv = tid >> 6;          // wv 0..7
  const int qw = wv & 3, kg = wv >> 2;
  const int lane31 = lane & 31, half = lane >> 5;
  const int x7 = lane & 7;
  const int bh = blockIdx.x, qt = blockIdx.y;
  const long long headoff = (long long)bh * N_;
  const int q0w = qt * 128 + qw * 32;
  const bool active = q0w < N_;            // wave-uniform; OOB waves only stage
  const int nreal = kg ? 8 : 9;            // tiles this k-group computes
  const int kbase = kg * 576;              // key offset of this k-group

  unsigned short* Ksm = smem;              // K tiles
  unsigned short* Vsm = smem + 16384;      // V^T tiles

  // Q fragments: lane holds Q[q=lane31][d = m*16 + half*8 + j]
  int gq = q0w + lane31; if (gq > N_ - 1) gq = N_ - 1;
  const unsigned short* qp = q + (headoff + gq) * HD_ + half * 8;
  bf16x8 qf[4];
#pragma unroll
  for (int m = 0; m < 4; m++) qf[m] = *(const bf16x8*)(qp + m * 16);

  // staging: per wave 2 issues per array per tile; issue t covers rows
  // t*32 + qw*8 + (lane>>3) of this kg's tile
  const unsigned short* kgp[2];
  const unsigned short* vgp[2];
#pragma unroll
  for (int t = 0; t < 2; t++) {
    const int r = t * 32 + qw * 8 + (lane >> 3);
    const int ch = (lane & 7) ^ (r & 7);
    kgp[t] = k + (headoff + kbase + r) * HD_ + ch * 8;
    vgp[t] = vt + ((long long)bh * HD_ + r) * NPAD + kbase + ch * 8;
  }

  f32x16 O0 = (f32x16)0.f, O1 = (f32x16)0.f;   // O[q=crow(r,half)][d=lane31+db*32]
  float l = 0.f;

  // prologue: stage this kg's tile 0 into buffer 0
#pragma unroll
  for (int t = 0; t < 2; t++) {
    gl2lds16(kgp[t], Ksm + (kg * 2 + 0) * 4096 + (t * 32 + qw * 8) * 64);
    gl2lds16(vgp[t], Vsm + (kg * 2 + 0) * 4096 + (t * 32 + qw * 8) * 64);
  }
  __syncthreads();

  for (int it = 0; it < 9; it++) {
    const int cur = it & 1;
    if (it + 1 < nreal) {
      const long long koff = (long long)(it + 1) * 64;
#pragma unroll
      for (int t = 0; t < 2; t++) {
        gl2lds16(kgp[t] + koff * HD_,
                 Ksm + (kg * 2 + (cur ^ 1)) * 4096 + (t * 32 + qw * 8) * 64);
        gl2lds16(vgp[t] + koff,
                 Vsm + (kg * 2 + (cur ^ 1)) * 4096 + (t * 32 + qw * 8) * 64);
      }
    }
    if (active && it < nreal) {
      const unsigned short* Kb = Ksm + (kg * 2 + cur) * 4096;
      const unsigned short* Vb = Vsm + (kg * 2 + cur) * 4096;
      // S^T = K Q^T  (log2e and 1/8 scale pre-folded into Q)
      f32x16 S0 = (f32x16)0.f, S1 = (f32x16)0.f;
      __builtin_amdgcn_s_setprio(1);
#pragma unroll
      for (int m = 0; m < 4; m++) {
        const int chs = ((m * 2 + half) ^ x7) * 8;
        const bf16x8 k0 = *(const bf16x8*)&Kb[lane31 * 64 + chs];
        const bf16x8 k1 = *(const bf16x8*)&Kb[(32 + lane31) * 64 + chs];
        S0 = __builtin_amdgcn_mfma_f32_32x32x16_bf16(k0, qf[m], S0, 0, 0, 0);
        S1 = __builtin_amdgcn_mfma_f32_32x32x16_bf16(k1, qf[m], S1, 0, 0, 0);
      }
      __builtin_amdgcn_s_setprio(0);
      if (kg == 1 && it == 7) {            // keys 1024..1087: mask OOB
#pragma unroll
        for (int r = 0; r < 16; r++) {
          const int kl = (r & 3) + 8 * (r >> 2) + 4 * half;
          if (1024 + kl >= N_) S0[r] = -1e30f;
          S1[r] = -1e30f;
        }
      }
      // P = 2^S in-register; pack pairs (k even,k odd) -> bf16 dwords
      unsigned pk0[8], pk1[8];
#pragma unroll
      for (int s = 0; s < 8; s++) {
        const float a0 = exp2f(S0[2 * s]), a1 = exp2f(S0[2 * s + 1]);
        const float b0 = exp2f(S1[2 * s]), b1 = exp2f(S1[2 * s + 1]);
        l += (a0 + a1) + (b0 + b1);
        pk0[s] = cvt_pk_bf16(a0, a1);
        pk1[s] = cvt_pk_bf16(b0, b1);
      }
      // assemble PV A-fragments via permlane32_swap (4 swaps per 32k-block)
      unsigned wkc[4][4];
#pragma unroll
      for (int bb = 0; bb < 2; bb++) {
#pragma unroll
        for (int kc2 = 0; kc2 < 2; kc2++) {
          unsigned a0 = bb ? pk1[kc2 * 4 + 0] : pk0[kc2 * 4 + 0];
          unsigned a2 = bb ? pk1[kc2 * 4 + 2] : pk0[kc2 * 4 + 2];
          permswap(a0, a2);
          unsigned a1 = bb ? pk1[kc2 * 4 + 1] : pk0[kc2 * 4 + 1];
          unsigned a3 = bb ? pk1[kc2 * 4 + 3] : pk0[kc2 * 4 + 3];
          permswap(a1, a3);
          const int kc = bb * 2 + kc2;
          wkc[kc][0] = a0; wkc[kc][1] = a1; wkc[kc][2] = a2; wkc[kc][3] = a3;
        }
      }
      // O += P V  (B-frag from Vt: V[k][d] = Vt[d][k], d=lane31+db*32)
      __builtin_amdgcn_s_setprio(1);
#pragma unroll
      for (int kc = 0; kc < 4; kc++) {
        union { unsigned u[4]; bf16x8 v; } pa;
        pa.u[0] = wkc[kc][0]; pa.u[1] = wkc[kc][1];
        pa.u[2] = wkc[kc][2]; pa.u[3] = wkc[kc][3];
        const int chv = ((kc * 2 + half) ^ x7) * 8;
        const bf16x8 v0 = *(const bf16x8*)&Vb[lane31 * 64 + chv];
        const bf16x8 v1 = *(const bf16x8*)&Vb[(32 + lane31) * 64 + chv];
        O0 = __builtin_amdgcn_mfma_f32_32x32x16_bf16(pa.v, v0, O0, 0, 0, 0);
        O1 = __builtin_amdgcn_mfma_f32_32x32x16_bf16(pa.v, v1, O1, 0, 0, 0);
      }
      __builtin_amdgcn_s_setprio(0);
    }
    // one barrier per tile: drains own async loads AND guards buffer reuse
    __syncthreads();
  }

  // ---- split-K merge: kg1 writes partial O,l; kg0 adds (LDS buffers dead) ----
  float* mrg = (float*)smem;               // [qw][33][64] f32 = 33792 B
  if (kg == 1 && active) {
    float* mq = mrg + qw * 33 * 64 + lane;
#pragma unroll
    for (int j = 0; j < 16; j++) mq[j * 64] = O0[j];
#pragma unroll
    for (int j = 0; j < 16; j++) mq[(16 + j) * 64] = O1[j];
    mq[32 * 64] = l;
  }
  __syncthreads();
  if (kg == 0 && active) {
    float* mq = mrg + qw * 33 * 64 + lane;
#pragma unroll
    for (int j = 0; j < 16; j++) O0[j] += mq[j * 64];
#pragma unroll
    for (int j = 0; j < 16; j++) O1[j] += mq[(16 + j) * 64];
    l += mq[32 * 64];

    // merge halves of l, redistribute 1/l to output rows
    l += __shfl_xor(l, 32, 64);
    const float rinv = 1.0f / l;
    float li[16];
#pragma unroll
    for (int r = 0; r < 16; r++) {
      const int qloc = (r & 3) + 8 * (r >> 2) + 4 * half;
      li[r] = __int_as_float(
          __builtin_amdgcn_ds_bpermute(qloc * 4, __float_as_int(rinv)));
    }
    const int b = bh / H_, hh = bh % H_;
#pragma unroll
    for (int r = 0; r < 16; r++) {
      const int qloc = (r & 3) + 8 * (r >> 2) + 4 * half;
      const int gqr = q0w + qloc;
      if (gqr < N_) {
        const long long orow = ((long long)b * N_ + gqr) * C_ + hh * HD_;
        o[orow + lane31] = f2us(O0[r] * li[r]);
        o[orow + 32 + lane31] = f2us(O1[r] * li[r]);
      }
    }
  }
}

// ---------------- Depthwise 3x3, 2 tokens/thread sliding window ----------------
// block = (b, i, j-pair); 192 threads each own 8 channels for both j0=2jp, j1=2jp+1.
// 12 uint4 data loads cover both outputs; weights unpacked once; shortcut = center taps.
__global__ __launch_bounds__(192) void dwconv_kernel(
    const unsigned short* __restrict__ y1, const unsigned short* __restrict__ w2s,
    const float* __restrict__ Bc, unsigned short* __restrict__ y2)
{
  const int jp = blockIdx.x & 15;
  const int i  = (blockIdx.x >> 4) & 31;
  const int b  = blockIdx.x >> 9;
  const int j0 = jp * 2;
  const int cb = threadIdx.x << 3;

  float wf[9][8];
#pragma unroll
  for (int tap = 0; tap < 9; tap++) {
    const uint4 wv = *(const uint4*)(w2s + tap * HID_ + cb);
    bf8_to_f(wv, wf[tap]);
  }
  float acc0[8] = {}, acc1[8] = {};
  float sh0[8], sh1[8];
#pragma unroll
  for (int di = -1; di <= 1; di++) {
    const int ii = i + di;
    if (ii < 0 || ii > 31) continue;
    const long long rowbase = ((long long)b * P_ + ii * 32) * HID_ + cb;
#pragma unroll
    for (int dj = -1; dj <= 2; dj++) {
      const int jj = j0 + dj;
      if (jj < 0 || jj > 31) continue;
      const uint4 dv = *(const uint4*)(y1 + rowbase + (long long)jj * HID_);
      float df[8]; bf8_to_f(dv, df);
      if (dj <= 1) {
        const int tap = (di + 1) * 3 + (dj + 1);
#pragma unroll
        for (int t = 0; t < 8; t++) acc0[t] += df[t] * wf[tap][t];
      }
      if (dj >= 0) {
        const int tap = (di + 1) * 3 + dj;
#pragma unroll
        for (int t = 0; t < 8; t++) acc1[t] += df[t] * wf[tap][t];
      }
      if (di == 0 && dj == 0) {
#pragma unroll
        for (int t = 0; t < 8; t++) sh0[t] = df[t];
      }
      if (di == 0 && dj == 1) {
#pragma unroll
        for (int t = 0; t < 8; t++) sh1[t] = df[t];
      }
    }
  }
  const float4 bc0 = *(const float4*)(Bc + cb);
  const float4 bc1 = *(const float4*)(Bc + cb + 4);
  const float bcv[8] = {bc0.x, bc0.y, bc0.z, bc0.w, bc1.x, bc1.y, bc1.z, bc1.w};
  float of0[8], of1[8];
#pragma unroll
  for (int t = 0; t < 8; t++) {
    of0[t] = sh0[t] + gelu_f(acc0[t] + bcv[t]);
    of1[t] = sh1[t] + gelu_f(acc1[t] + bcv[t]);
  }
  const long long tok0 = ((long long)b * P_ + i * 32 + j0) * HID_ + cb;
  *(uint4*)(y2 + tok0) = f_to_bf8(of0);
  *(uint4*)(y2 + tok0 + HID_) = f_to_bf8(of1);
}

// ---------------- Spatial pooling (two-stage, no atomics) ----------------
__global__ __launch_bounds__(384) void pool_kernel(const float* __restrict__ y3,
                                                   float* __restrict__ w0p)
{
  const int b = blockIdx.x, chunk = blockIdx.y;
  const int c = threadIdx.x;
  float s = 0.f;
  for (int p = chunk * 64; p < chunk * 64 + 64; p++)
    s += y3[((long long)b * P_ + p) * C_ + c];
  w0p[((long long)b * 16 + chunk) * C_ + c] = s;
}

// ---------------- Squeeze-excite MLP ----------------
__global__ __launch_bounds__(128) void se_kernel(
    const float* __restrict__ w0p, const float* __restrict__ cw,
    const float* __restrict__ cb, const float* __restrict__ ew,
    const float* __restrict__ eb, float* __restrict__ wfin)
{
  __shared__ float wm[384];
  __shared__ float t1[96];
  const int b = blockIdx.x, t = threadIdx.x;
  for (int c = t; c < 384; c += 128) {
    float s = 0.f;
    for (int ch = 0; ch < 16; ch++) s += w0p[((long long)b * 16 + ch) * C_ + c];
    wm[c] = s * (1.0f / 1024.0f);
  }
  __syncthreads();
  if (t < 96) {
    float s = cb[t];
    for (int c = 0; c < 384; c++) s += wm[c] * cw[t * 384 + c];
    t1[t] = gelu_f(s);
  }
  __syncthreads();
  for (int c = t; c < 384; c += 128) {
    float s = eb[c];
    for (int j = 0; j < 96; j++) s += t1[j] * ew[c * 96 + j];
    wfin[(long long)b * C_ + c] = s;
  }
}

// ---------------- cls rows: out[b,0,:] = x2[b,0,:] + cls*wfin ----------------
__global__ __launch_bounds__(256) void clsfix_kernel(
    const float* __restrict__ x2, const float* __restrict__ cls,
    const float* __restrict__ wfin, float* __restrict__ out)
{
  const int idx = blockIdx.x * 256 + threadIdx.x;
  if (idx >= B_ * C_) return;
  const int b = idx / C_, c = idx % C_;
  const long long row = (long long)b * N_ * C_ + c;
  out[row] = x2[row] + cls[idx] * wfin[idx];
}

}  // namespace

// Workspace layout (bytes), total ~130 MiB:
//   RegionA [0, 50331648):            q,k,v bf16 -> h2 bf16 -> y2 bf16
//   RegionB [50331648, 100663296):    h bf16 -> o_mat bf16 -> y1 bf16 -> y3 fp32
//   RegionC [100663296, 125853696):   vT bf16 (during attention) -> x2 fp32
//   tail:                             bf16 weights(contig)+w2s, Bc, cls, w0p, wfin
extern "C" void kernel_launch(void* const* d_in, const int* in_sizes, int n_in,
                              void* d_out, int out_size, void* d_ws, size_t ws_size,
                              hipStream_t stream)
{
  const float* x       = (const float*)d_in[0];
  const float* ln1_g   = (const float*)d_in[1];
  const float* ln1_b   = (const float*)d_in[2];
  const float* qkv_w   = (const float*)d_in[3];
  const float* proj_w  = (const float*)d_in[4];
  const float* proj_b  = (const float*)d_in[5];
  const float* ln2_g   = (const float*)d_in[6];
  const float* ln2_b   = (const float*)d_in[7];
  const float* conv1_w = (const float*)d_in[8];
  const float* conv1_b = (const float*)d_in[9];
  const float* conv2_w = (const float*)d_in[10];
  const float* conv2_b = (const float*)d_in[11];
  const float* conv3_w = (const float*)d_in[12];
  const float* conv3_b = (const float*)d_in[13];
  const float* bn1_s   = (const float*)d_in[14];
  const float* bn1_b   = (const float*)d_in[15];
  const float* bn2_s   = (const float*)d_in[16];
  const float* bn2_b   = (const float*)d_in[17];
  const float* bn3_s   = (const float*)d_in[18];
  const float* bn3_b   = (const float*)d_in[19];
  const float* comp_w  = (const float*)d_in[20];
  const float* comp_b  = (const float*)d_in[21];
  const float* exc_w   = (const float*)d_in[22];
  const float* exc_b   = (const float*)d_in[23];

  char* wsb = (char*)d_ws;
  const size_t RA = 50331648, RB = 50331648, RC = 25190400;
  const size_t tailbytes = (size_t)T5 * 2 +
                           (size_t)(HID_ + B_ * C_ + B_ * 16 * C_ + B_ * C_) * 4;
  const size_t needed = RA + RB + RC + tailbytes;
  if (ws_size < needed) return;

  unsigned short* qb  = (unsigned short*)wsb;
  unsigned short* kb  = qb + AF;
  unsigned short* vb  = kb + AF;
  unsigned short* h2b = (unsigned short*)wsb;          // overlay RA
  unsigned short* y2  = (unsigned short*)wsb;          // overlay RA
  char* rb = wsb + RA;
  unsigned short* hb  = (unsigned short*)rb;           // LN1 out
  unsigned short* o16 = (unsigned short*)rb;           // attn out (overlay)
  unsigned short* y1  = (unsigned short*)rb;           // conv1 out (overlay)
  float* y3           = (float*)rb;                    // conv3 out (overlay)
  unsigned short* vtb = (unsigned short*)(wsb + RA + RB);  // V^T (overlay RC)
  float* x2 = (float*)(wsb + RA + RB);                     // x2 after attention
  unsigned short* w16 = (unsigned short*)(wsb + RA + RB + RC);  // contiguous weights
  unsigned short* wqkv16  = w16;
  unsigned short* wproj16 = w16 + T1;
  unsigned short* wc116   = w16 + T2;
  unsigned short* wc316   = w16 + T3;
  unsigned short* w2s     = w16 + T4;
  float* Bc   = (float*)(w16 + T5);
  float* cls  = Bc + HID_;
  float* w0p  = cls + B_ * C_;
  float* wfin = w0p + B_ * 16 * C_;

  // 0. fused weight conversion / prep (1 launch)
  cvtall_kernel<<<(T6 + 255) / 256, 256, 0, stream>>>(
      qkv_w, proj_w, conv1_w, conv3_w, conv2_w, conv2_b, bn2_s, bn2_b, w16, Bc);
  // 1. LN1 -> bf16 (wave-per-row)
  lnw_kernel<<<(MALL + 3) / 4, 256, 0, stream>>>(x, ln1_g, ln1_b, hb, nullptr, MALL);
  // 2. QKV MFMA GEMM (Q pre-scaled by 0.125*log2e)
  mgemm_kernel<GM_QKV, 384><<<dim3(136, 9), 256, 0, stream>>>(
      hb, wqkv16, qb, kb, vb, nullptr, nullptr, nullptr, MALL);
  // 2b. V transpose -> vT (bh, d, n) padded
  vtrans_kernel<<<dim3(B_ * H_, 17), 256, 0, stream>>>(vb, vtb);
  // 3. Flash attention (32x32 swapped-QK^T, in-register softmax, split-K x2)
  fattn_kernel<<<dim3(B_ * H_, 9), 512, 0, stream>>>(qb, kb, vtb, o16);
  // 4. proj MFMA GEMM + residual -> x2 fp32 (overwrites vT region)
  mgemm_kernel<GM_PROJ, 384><<<dim3(136, 3), 256, 0, stream>>>(
      o16, wproj16, x2, nullptr, nullptr, x, proj_b, nullptr, MALL);
  // 5. LN2 -> bf16 h2 (+ fp32 cls rows)
  lnw_kernel<<<(MALL + 3) / 4, 256, 0, stream>>>(x2, ln2_g, ln2_b, h2b, cls, MALL);
  // 6. conv1 MFMA GEMM + bias/BN/GELU -> y1 bf16
  mgemm_kernel<GM_CONV1, 384><<<dim3(128, 12), 256, 0, stream>>>(
      h2b, wc116, y1, nullptr, nullptr, conv1_b, bn1_s, bn1_b, MTOK);
  // 7. depthwise 3x3 (2 tokens/thread) -> y2 bf16
  dwconv_kernel<<<B_ * 32 * 16, 192, 0, stream>>>(y1, w2s, Bc, y2);
  // 8. conv3 MFMA GEMM + bias/BN -> y3 fp32 AND out tokens (= x2 + y3)
  mgemm_kernel<GM_CONV3, 1536><<<dim3(128, 3), 256, 0, stream>>>(
      y2, wc316, y3, (float*)d_out, x2, conv3_b, bn3_s, bn3_b, MTOK);
  // 9. pool, 10. SE
  pool_kernel<<<dim3(B_, 16), 384, 0, stream>>>(y3, w0p);
  se_kernel<<<B_, 128, 0, stream>>>(w0p, comp_w, comp_b, exc_w, exc_b, wfin);
  // 11. cls rows of out
  clsfix_kernel<<<(B_ * C_ + 255) / 256, 256, 0, stream>>>(x2, cls, wfin, (float*)d_out);
}